// Round 2
// baseline (367.490 us; speedup 1.0000x reference)
//
#include <hip/hip_runtime.h>

typedef __attribute__((ext_vector_type(8))) short s16x8;
typedef __attribute__((ext_vector_type(4))) float f32x4;
typedef unsigned short u16;
typedef unsigned int u32;
typedef unsigned long long u64;

// ---------- helpers ----------
__device__ __forceinline__ u16 f2bf(float f) {            // RNE f32 -> bf16
  u32 u = __builtin_bit_cast(u32, f);
  u += 0x7fff + ((u >> 16) & 1);
  return (u16)(u >> 16);
}

__device__ __forceinline__ float exp2fast(float x) {
#if __has_builtin(__builtin_amdgcn_exp2f)
  return __builtin_amdgcn_exp2f(x);
#else
  return __expf(x * 0.6931471805599453f);
#endif
}

__device__ __forceinline__ void gload16(const void* g, void* l) {
  __builtin_amdgcn_global_load_lds((const __attribute__((address_space(1))) u32*)g,
                                   (__attribute__((address_space(3))) u32*)l, 16, 0, 0);
}

#define MFMA(a, b, c) __builtin_amdgcn_mfma_f32_16x16x32_bf16((a), (b), (c), 0, 0, 0)

// ---------- fp32 -> bf16 convert (8 elems/thread) ----------
__global__ __launch_bounds__(256) void cvt_bf16(const float* __restrict__ src,
                                                u16* __restrict__ dst, int n8) {
  int i = blockIdx.x * 256 + threadIdx.x;
  if (i >= n8) return;
  const float4* s4 = (const float4*)src;
  float4 a = s4[2 * i], b = s4[2 * i + 1];
  uint4 o;
  o.x = (u32)f2bf(a.x) | ((u32)f2bf(a.y) << 16);
  o.y = (u32)f2bf(a.z) | ((u32)f2bf(a.w) << 16);
  o.z = (u32)f2bf(b.x) | ((u32)f2bf(b.y) << 16);
  o.w = (u32)f2bf(b.z) | ((u32)f2bf(b.w) << 16);
  ((uint4*)dst)[i] = o;
}

// ---------- mask int32 [B,S,S] -> bitmask u64 [B,S,S/64] ----------
__global__ __launch_bounds__(256) void mask_bits(const int* __restrict__ mask,
                                                 u64* __restrict__ mb) {
  int wi = (blockIdx.x * 256 + threadIdx.x) >> 6;   // u64 index, one wave each
  int lane = threadIdx.x & 63;
  u64 bits = __ballot(mask[((size_t)wi << 6) + lane] != 0);
  if (lane == 0) mb[wi] = bits;
}

// ---------- W [1024][1024] f32 -> WT [1024][1024] bf16 ----------
__global__ __launch_bounds__(256) void transpose_w_k(const float* __restrict__ W,
                                                     u16* __restrict__ WT) {
  __shared__ float t[32][33];
  int tx = threadIdx.x, ty = threadIdx.y;
  int n = blockIdx.x * 32 + tx;
#pragma unroll
  for (int j = 0; j < 4; j++) {
    int k = blockIdx.y * 32 + ty + 8 * j;
    t[ty + 8 * j][tx] = W[(size_t)k * 1024 + n];
  }
  __syncthreads();
  int k = blockIdx.y * 32 + tx;
#pragma unroll
  for (int j = 0; j < 4; j++) {
    int n2 = blockIdx.x * 32 + ty + 8 * j;
    WT[(size_t)n2 * 1024 + k] = f2bf(t[tx][ty + 8 * j]);
  }
}

// ---------- shared GEMM core: C[BMxBN] = A[m0..][K=1024] * BT[n0..][K=1024]^T ----------
template <int BM, int BN>
__device__ __forceinline__ void gemm_core(const u16* __restrict__ A, const u16* __restrict__ BT,
                                          int m0, int n0, u16* Ash, u16* Bsh,
                                          f32x4 (&acc)[BM / 32][BN / 32]) {
  constexpr int MF = BM / 32, NF = BN / 32;
  const int tid = threadIdx.x;
  const int lane = tid & 63, wid = tid >> 6;
  const int r16 = lane & 15, g = lane >> 4;
  const int wm = wid >> 1, wn = wid & 1;
  const f32x4 vz = {0.f, 0.f, 0.f, 0.f};
#pragma unroll
  for (int mf = 0; mf < MF; mf++)
#pragma unroll
    for (int nf = 0; nf < NF; nf++) acc[mf][nf] = vz;

  for (int k0 = 0; k0 < 1024; k0 += 64) {
#pragma unroll
    for (int i = 0; i < BM / 32; i++) {
      int ch = i * 256 + tid;
      gload16((const char*)A + (((size_t)(m0 + (ch >> 3)) << 10) + k0 + ((ch & 7) << 3)) * 2,
              (char*)Ash + ch * 16);
    }
#pragma unroll
    for (int i = 0; i < BN / 32; i++) {
      int ch = i * 256 + tid;
      gload16((const char*)BT + (((size_t)(n0 + (ch >> 3)) << 10) + k0 + ((ch & 7) << 3)) * 2,
              (char*)Bsh + ch * 16);
    }
    __syncthreads();
#pragma unroll
    for (int kk = 0; kk < 2; kk++) {
      s16x8 af[MF], bfr[NF];
#pragma unroll
      for (int mf = 0; mf < MF; mf++)
        af[mf] = *(const s16x8*)(Ash + ((wm * (BM / 2) + mf * 16 + r16) << 6) + kk * 32 + g * 8);
#pragma unroll
      for (int nf = 0; nf < NF; nf++)
        bfr[nf] = *(const s16x8*)(Bsh + ((wn * (BN / 2) + nf * 16 + r16) << 6) + kk * 32 + g * 8);
#pragma unroll
      for (int mf = 0; mf < MF; mf++)
#pragma unroll
        for (int nf = 0; nf < NF; nf++) acc[mf][nf] = MFMA(af[mf], bfr[nf], acc[mf][nf]);
    }
    __syncthreads();
  }
}

// ---------- fused QKV projection: z=0 Q, z=1 K (head-major), z=2 V (transposed) ----------
__global__ __launch_bounds__(256) void proj_gemm(
    const u16* __restrict__ Xq, const u16* __restrict__ Xk, const u16* __restrict__ Xv,
    const u16* __restrict__ WqT, const u16* __restrict__ WkT, const u16* __restrict__ WvT,
    const float* __restrict__ bq, const float* __restrict__ bk, const float* __restrict__ bv,
    u16* __restrict__ Qo, u16* __restrict__ Ko, u16* __restrict__ Vto) {
  __shared__ u16 Ash[128 * 64], Bsh[128 * 64];
  const int z = blockIdx.z;
  const u16* A = (z == 0) ? Xq : (z == 1) ? Xk : Xv;
  const u16* BT = (z == 0) ? WqT : (z == 1) ? WkT : WvT;
  const float* bias = (z == 0) ? bq : (z == 1) ? bk : bv;
  u16* O = (z == 0) ? Qo : (z == 1) ? Ko : Vto;
  const int m0 = blockIdx.y * 128, n0 = blockIdx.x * 128;
  f32x4 acc[4][4];
  gemm_core<128, 128>(A, BT, m0, n0, Ash, Bsh, acc);
  const int tid = threadIdx.x, lane = tid & 63, wid = tid >> 6;
  const int r16 = lane & 15, g = lane >> 4, wm = wid >> 1, wn = wid & 1;
#pragma unroll
  for (int nf = 0; nf < 4; nf++) {
    int col = n0 + wn * 64 + nf * 16 + r16;
    float bb = bias[col];
    int h = col >> 6, d = col & 63;
#pragma unroll
    for (int mf = 0; mf < 4; mf++) {
#pragma unroll
      for (int ri = 0; ri < 4; ri++) {
        int row = m0 + wm * 64 + mf * 16 + g * 4 + ri;
        int b_ = row >> 11, s_ = row & 2047;
        u16 val = f2bf(acc[mf][nf][ri] + bb);
        if (z < 2)
          O[((((size_t)b_ * 16 + h) * 2048 + s_) << 6) + d] = val;     // [B,H,S,64]
        else
          O[((((size_t)b_ * 16 + h) * 64 + d) << 11) + s_] = val;     // [B,H,64,S]
      }
    }
  }
}

// ---------- output projection: out = ctx @ WoT^T + bo (fp32) ----------
__global__ __launch_bounds__(256) void out_gemm(const u16* __restrict__ ctx,
                                                const u16* __restrict__ WoT,
                                                const float* __restrict__ bo,
                                                float* __restrict__ out) {
  __shared__ u16 Ash[64 * 64], Bsh[128 * 64];
  const int m0 = blockIdx.y * 64, n0 = blockIdx.x * 128;
  f32x4 acc[2][4];
  gemm_core<64, 128>(ctx, WoT, m0, n0, Ash, Bsh, acc);
  const int tid = threadIdx.x, lane = tid & 63, wid = tid >> 6;
  const int r16 = lane & 15, g = lane >> 4, wm = wid >> 1, wn = wid & 1;
#pragma unroll
  for (int nf = 0; nf < 4; nf++) {
    int col = n0 + wn * 64 + nf * 16 + r16;
    float bb = bo[col];
#pragma unroll
    for (int mf = 0; mf < 2; mf++) {
#pragma unroll
      for (int ri = 0; ri < 4; ri++) {
        int row = m0 + wm * 32 + mf * 16 + g * 4 + ri;
        out[((size_t)row << 10) + col] = acc[mf][nf][ri] + bb;
      }
    }
  }
}

// ---------- flash attention v2: swapped QK^T, no-max softmax, bitmask ----------
// block = (q-tile 64, h, b); 4 waves x 16 q-rows; per-wave P tile in LDS.
__global__ __launch_bounds__(256, 4) void flash_attn(const u16* __restrict__ Q,
                                                     const u16* __restrict__ K,
                                                     const u16* __restrict__ Vt,
                                                     const u64* __restrict__ Mb64,
                                                     u16* __restrict__ ctx) {
  __shared__ __align__(16) u16 P[4][16][72];  // stride 72 u16 = 144B: uniform banks for b64 W / b128 R
  const int tid = threadIdx.x, w = tid >> 6, lane = tid & 63;
  const int r16 = lane & 15, g = lane >> 4;
  const int b = blockIdx.z, h = blockIdx.y;
  const int q0 = blockIdx.x * 64 + w * 16;
  const u16* Qb = Q + ((size_t)(b * 16 + h) << 17);
  const u16* Kb = K + ((size_t)(b * 16 + h) << 17);
  const u16* Vb = Vt + ((size_t)(b * 16 + h) << 17);
  const u64* Mrow = Mb64 + ((size_t)(b * 2048 + q0 + r16) << 5);  // 32 u64 per row
  u16* Pw = &P[w][0][0];

  // Q as B-fragment: lane r16 <-> q-col, elems d = c*32+g*8..+7
  s16x8 aq[2];
#pragma unroll
  for (int c = 0; c < 2; c++) aq[c] = *(const s16x8*)(Qb + ((q0 + r16) << 6) + c * 32 + g * 8);

  const f32x4 vz = {0.f, 0.f, 0.f, 0.f};
  f32x4 o[4];
#pragma unroll
  for (int i = 0; i < 4; i++) o[i] = vz;
  float rs = 0.f;                       // per-lane partial row-sum (q = r16)
  const float C2 = 0.125f * 1.44269504088896f;  // scale * log2(e)

  for (int kv0 = 0; kv0 < 2048; kv0 += 64) {
    u64 m = Mrow[kv0 >> 6] >> (g * 4);  // lane's bits now at nt*16+ri
    u32 mlo = (u32)m, mhi = (u32)(m >> 32);

    // S^T = K @ Q^T : s_[nt][ri] = score(q=r16, k=kv0+nt*16+g*4+ri)
    f32x4 s_[4];
#pragma unroll
    for (int nt = 0; nt < 4; nt++) s_[nt] = vz;
#pragma unroll
    for (int c = 0; c < 2; c++) {
#pragma unroll
      for (int nt = 0; nt < 4; nt++) {
        s16x8 ak = *(const s16x8*)(Kb + ((kv0 + nt * 16 + r16) << 6) + c * 32 + g * 8);
        s_[nt] = MFMA(ak, aq[c], s_[nt]);
      }
    }

    // p = exp2(s*C2) * maskbit ; accumulate per-lane row-sum; pack to bf16 pairs
#pragma unroll
    for (int nt = 0; nt < 4; nt++) {
      u32 word = (nt < 2) ? mlo : mhi;
      float e0, e1, e2, e3;
      {
        u32 b0 = (word >> (((nt & 1) << 4) + 0)) & 1;
        u32 b1 = (word >> (((nt & 1) << 4) + 1)) & 1;
        u32 b2 = (word >> (((nt & 1) << 4) + 2)) & 1;
        u32 b3 = (word >> (((nt & 1) << 4) + 3)) & 1;
        e0 = exp2fast(s_[nt][0] * C2) * (float)b0;
        e1 = exp2fast(s_[nt][1] * C2) * (float)b1;
        e2 = exp2fast(s_[nt][2] * C2) * (float)b2;
        e3 = exp2fast(s_[nt][3] * C2) * (float)b3;
      }
      rs += (e0 + e1) + (e2 + e3);
      u32 pk0, pk1;
      asm("v_cvt_pk_bf16_f32 %0, %1, %2" : "=v"(pk0) : "v"(e0), "v"(e1));
      asm("v_cvt_pk_bf16_f32 %0, %1, %2" : "=v"(pk1) : "v"(e2), "v"(e3));
      uint2 pr; pr.x = pk0; pr.y = pk1;
      // P[q=r16][k = nt*16+g*4 .. +3]
      *(uint2*)((char*)Pw + r16 * 144 + nt * 32 + g * 8) = pr;
    }
    asm volatile("" ::: "memory");  // same-wave LDS write -> read ordering

    // PV: o[nt_d] += P(A-frag) @ Vt(B-frag)
#pragma unroll
    for (int c = 0; c < 2; c++) {
      s16x8 pa = *(const s16x8*)((char*)Pw + r16 * 144 + c * 64 + g * 16);
#pragma unroll
      for (int nt = 0; nt < 4; nt++) {
        s16x8 bv = *(const s16x8*)(Vb + ((size_t)(nt * 16 + r16) << 11) + kv0 + c * 32 + g * 8);
        o[nt] = MFMA(pa, bv, o[nt]);
      }
    }
    asm volatile("" ::: "memory");
  }

  // final row-sum reduce across g-groups (lane's rs covers its k-subset of all tiles)
  rs += __shfl_xor(rs, 16, 64);
  rs += __shfl_xor(rs, 32, 64);
  float inv = 1.f / rs;               // valid for q = r16 on every lane
  float invq[4];
#pragma unroll
  for (int ri = 0; ri < 4; ri++) invq[ri] = __shfl(inv, g * 4 + ri, 64);  // q = g*4+ri

  // o[nt][ri] = ctx[q=g*4+ri][d=nt*16+r16]; write ctx bf16 [B*S][1024]
#pragma unroll
  for (int nt = 0; nt < 4; nt++) {
    int col = (h << 6) + nt * 16 + r16;
#pragma unroll
    for (int ri = 0; ri < 4; ri++) {
      int row = (b << 11) + q0 + g * 4 + ri;
      ctx[((size_t)row << 10) + col] = f2bf(o[nt][ri] * invq[ri]);
    }
  }
}

// ---------- host ----------
extern "C" void kernel_launch(void* const* d_in, const int* in_sizes, int n_in,
                              void* d_out, int out_size, void* d_ws, size_t ws_size,
                              hipStream_t stream) {
  const float* query = (const float*)d_in[0];
  const float* key_  = (const float*)d_in[1];
  const float* value = (const float*)d_in[2];
  const int*   mask  = (const int*)d_in[3];
  const float* Wq = (const float*)d_in[4];
  const float* bq = (const float*)d_in[5];
  const float* Wk = (const float*)d_in[6];
  const float* bk = (const float*)d_in[7];
  const float* Wv = (const float*)d_in[8];
  const float* bv = (const float*)d_in[9];
  const float* Wo = (const float*)d_in[10];
  const float* bo = (const float*)d_in[11];

  const size_t MB = 1048576;
  char* ws = (char*)d_ws;
  u16* Xq  = (u16*)(ws + 0 * MB);
  u16* Xk  = (u16*)(ws + 8 * MB);
  u16* Xv  = (u16*)(ws + 16 * MB);
  u16* WqT = (u16*)(ws + 24 * MB);
  u16* WkT = (u16*)(ws + 26 * MB);
  u16* WvT = (u16*)(ws + 28 * MB);
  u16* WoT = (u16*)(ws + 30 * MB);
  u16* Qd  = (u16*)(ws + 32 * MB);
  u16* Kd  = (u16*)(ws + 40 * MB);
  u16* Vtd = (u16*)(ws + 48 * MB);
  u16* ctx = (u16*)(ws + 56 * MB);
  u64* Mb  = (u64*)(ws + 72 * MB);   // 1 MB bitmask

  cvt_bf16<<<2048, 256, 0, stream>>>(query, Xq, 524288);
  cvt_bf16<<<2048, 256, 0, stream>>>(key_,  Xk, 524288);
  cvt_bf16<<<2048, 256, 0, stream>>>(value, Xv, 524288);
  mask_bits<<<32768, 256, 0, stream>>>(mask, Mb);

  dim3 tb(32, 8);
  transpose_w_k<<<dim3(32, 32), tb, 0, stream>>>(Wq, WqT);
  transpose_w_k<<<dim3(32, 32), tb, 0, stream>>>(Wk, WkT);
  transpose_w_k<<<dim3(32, 32), tb, 0, stream>>>(Wv, WvT);
  transpose_w_k<<<dim3(32, 32), tb, 0, stream>>>(Wo, WoT);

  proj_gemm<<<dim3(8, 32, 3), 256, 0, stream>>>(Xq, Xk, Xv, WqT, WkT, WvT, bq, bk, bv,
                                                Qd, Kd, Vtd);
  flash_attn<<<dim3(32, 16, 2), 256, 0, stream>>>(Qd, Kd, Vtd, Mb, ctx);
  out_gemm<<<dim3(8, 64), 256, 0, stream>>>(ctx, WoT, bo, (float*)d_out);
}

// Round 3
// 206.841 us; speedup vs baseline: 1.7767x; 1.7767x over previous
//
#include <hip/hip_runtime.h>

typedef __attribute__((ext_vector_type(8))) short s16x8;
typedef __attribute__((ext_vector_type(4))) float f32x4;
typedef unsigned short u16;
typedef unsigned int u32;
typedef unsigned long long u64;

// ---------- helpers ----------
__device__ __forceinline__ u16 f2bf(float f) {            // RNE f32 -> bf16
  u32 u = __builtin_bit_cast(u32, f);
  u += 0x7fff + ((u >> 16) & 1);
  return (u16)(u >> 16);
}

__device__ __forceinline__ float exp2fast(float x) {
#if __has_builtin(__builtin_amdgcn_exp2f)
  return __builtin_amdgcn_exp2f(x);
#else
  return __expf(x * 0.6931471805599453f);
#endif
}

__device__ __forceinline__ void gload16(const void* g, void* l) {
  __builtin_amdgcn_global_load_lds((const __attribute__((address_space(1))) u32*)g,
                                   (__attribute__((address_space(3))) u32*)l, 16, 0, 0);
}

#define MFMA(a, b, c) __builtin_amdgcn_mfma_f32_16x16x32_bf16((a), (b), (c), 0, 0, 0)

// ---------- fp32 -> bf16 convert (8 elems/thread) ----------
__global__ __launch_bounds__(256) void cvt_bf16(const float* __restrict__ src,
                                                u16* __restrict__ dst, int n8) {
  int i = blockIdx.x * 256 + threadIdx.x;
  if (i >= n8) return;
  const float4* s4 = (const float4*)src;
  float4 a = s4[2 * i], b = s4[2 * i + 1];
  uint4 o;
  o.x = (u32)f2bf(a.x) | ((u32)f2bf(a.y) << 16);
  o.y = (u32)f2bf(a.z) | ((u32)f2bf(a.w) << 16);
  o.z = (u32)f2bf(b.x) | ((u32)f2bf(b.y) << 16);
  o.w = (u32)f2bf(b.z) | ((u32)f2bf(b.w) << 16);
  ((uint4*)dst)[i] = o;
}

// ---------- mask int32 [B,S,S] -> bitmask u64 [B,S,S/64] ----------
__global__ __launch_bounds__(256) void mask_bits(const int* __restrict__ mask,
                                                 u64* __restrict__ mb) {
  int wi = (blockIdx.x * 256 + threadIdx.x) >> 6;   // u64 index, one wave each
  int lane = threadIdx.x & 63;
  u64 bits = __ballot(mask[((size_t)wi << 6) + lane] != 0);
  if (lane == 0) mb[wi] = bits;
}

// ---------- W [1024][1024] f32 -> WT [1024][1024] bf16 ----------
__global__ __launch_bounds__(256) void transpose_w_k(const float* __restrict__ W,
                                                     u16* __restrict__ WT) {
  __shared__ float t[32][33];
  int tx = threadIdx.x, ty = threadIdx.y;
  int n = blockIdx.x * 32 + tx;
#pragma unroll
  for (int j = 0; j < 4; j++) {
    int k = blockIdx.y * 32 + ty + 8 * j;
    t[ty + 8 * j][tx] = W[(size_t)k * 1024 + n];
  }
  __syncthreads();
  int k = blockIdx.y * 32 + tx;
#pragma unroll
  for (int j = 0; j < 4; j++) {
    int n2 = blockIdx.x * 32 + ty + 8 * j;
    WT[(size_t)n2 * 1024 + k] = f2bf(t[tx][ty + 8 * j]);
  }
}

// ---------- shared GEMM core: C[BMxBN] = A[m0..][K=1024] * BT[n0..][K=1024]^T ----------
template <int BM, int BN>
__device__ __forceinline__ void gemm_core(const u16* __restrict__ A, const u16* __restrict__ BT,
                                          int m0, int n0, u16* Ash, u16* Bsh,
                                          f32x4 (&acc)[BM / 32][BN / 32]) {
  constexpr int MF = BM / 32, NF = BN / 32;
  const int tid = threadIdx.x;
  const int lane = tid & 63, wid = tid >> 6;
  const int r16 = lane & 15, g = lane >> 4;
  const int wm = wid >> 1, wn = wid & 1;
  const f32x4 vz = {0.f, 0.f, 0.f, 0.f};
#pragma unroll
  for (int mf = 0; mf < MF; mf++)
#pragma unroll
    for (int nf = 0; nf < NF; nf++) acc[mf][nf] = vz;

  for (int k0 = 0; k0 < 1024; k0 += 64) {
#pragma unroll
    for (int i = 0; i < BM / 32; i++) {
      int ch = i * 256 + tid;
      gload16((const char*)A + (((size_t)(m0 + (ch >> 3)) << 10) + k0 + ((ch & 7) << 3)) * 2,
              (char*)Ash + ch * 16);
    }
#pragma unroll
    for (int i = 0; i < BN / 32; i++) {
      int ch = i * 256 + tid;
      gload16((const char*)BT + (((size_t)(n0 + (ch >> 3)) << 10) + k0 + ((ch & 7) << 3)) * 2,
              (char*)Bsh + ch * 16);
    }
    __syncthreads();
#pragma unroll
    for (int kk = 0; kk < 2; kk++) {
      s16x8 af[MF], bfr[NF];
#pragma unroll
      for (int mf = 0; mf < MF; mf++)
        af[mf] = *(const s16x8*)(Ash + ((wm * (BM / 2) + mf * 16 + r16) << 6) + kk * 32 + g * 8);
#pragma unroll
      for (int nf = 0; nf < NF; nf++)
        bfr[nf] = *(const s16x8*)(Bsh + ((wn * (BN / 2) + nf * 16 + r16) << 6) + kk * 32 + g * 8);
#pragma unroll
      for (int mf = 0; mf < MF; mf++)
#pragma unroll
        for (int nf = 0; nf < NF; nf++) acc[mf][nf] = MFMA(af[mf], bfr[nf], acc[mf][nf]);
    }
    __syncthreads();
  }
}

// ---------- fused QKV projection: z=0 Q, z=1 K (head-major), z=2 V (transposed) ----------
__global__ __launch_bounds__(256) void proj_gemm(
    const u16* __restrict__ Xq, const u16* __restrict__ Xk, const u16* __restrict__ Xv,
    const u16* __restrict__ WqT, const u16* __restrict__ WkT, const u16* __restrict__ WvT,
    const float* __restrict__ bq, const float* __restrict__ bk, const float* __restrict__ bv,
    u16* __restrict__ Qo, u16* __restrict__ Ko, u16* __restrict__ Vto) {
  __shared__ u16 Ash[128 * 64], Bsh[128 * 64];
  const int z = blockIdx.z;
  const u16* A = (z == 0) ? Xq : (z == 1) ? Xk : Xv;
  const u16* BT = (z == 0) ? WqT : (z == 1) ? WkT : WvT;
  const float* bias = (z == 0) ? bq : (z == 1) ? bk : bv;
  u16* O = (z == 0) ? Qo : (z == 1) ? Ko : Vto;
  const int m0 = blockIdx.y * 128, n0 = blockIdx.x * 128;
  f32x4 acc[4][4];
  gemm_core<128, 128>(A, BT, m0, n0, Ash, Bsh, acc);
  const int tid = threadIdx.x, lane = tid & 63, wid = tid >> 6;
  const int r16 = lane & 15, g = lane >> 4, wm = wid >> 1, wn = wid & 1;
#pragma unroll
  for (int nf = 0; nf < 4; nf++) {
    int col = n0 + wn * 64 + nf * 16 + r16;
    float bb = bias[col];
    int h = col >> 6, d = col & 63;
#pragma unroll
    for (int mf = 0; mf < 4; mf++) {
#pragma unroll
      for (int ri = 0; ri < 4; ri++) {
        int row = m0 + wm * 64 + mf * 16 + g * 4 + ri;
        int b_ = row >> 11, s_ = row & 2047;
        u16 val = f2bf(acc[mf][nf][ri] + bb);
        if (z < 2)
          O[((((size_t)b_ * 16 + h) * 2048 + s_) << 6) + d] = val;     // [B,H,S,64]
        else
          O[((((size_t)b_ * 16 + h) * 64 + d) << 11) + s_] = val;     // [B,H,64,S]
      }
    }
  }
}

// ---------- output projection: out = ctx @ WoT^T + bo (fp32) ----------
__global__ __launch_bounds__(256) void out_gemm(const u16* __restrict__ ctx,
                                                const u16* __restrict__ WoT,
                                                const float* __restrict__ bo,
                                                float* __restrict__ out) {
  __shared__ u16 Ash[64 * 64], Bsh[128 * 64];
  const int m0 = blockIdx.y * 64, n0 = blockIdx.x * 128;
  f32x4 acc[2][4];
  gemm_core<64, 128>(ctx, WoT, m0, n0, Ash, Bsh, acc);
  const int tid = threadIdx.x, lane = tid & 63, wid = tid >> 6;
  const int r16 = lane & 15, g = lane >> 4, wm = wid >> 1, wn = wid & 1;
#pragma unroll
  for (int nf = 0; nf < 4; nf++) {
    int col = n0 + wn * 64 + nf * 16 + r16;
    float bb = bo[col];
#pragma unroll
    for (int mf = 0; mf < 2; mf++) {
#pragma unroll
      for (int ri = 0; ri < 4; ri++) {
        int row = m0 + wm * 32 + mf * 16 + g * 4 + ri;
        out[((size_t)row << 10) + col] = acc[mf][nf][ri] + bb;
      }
    }
  }
}

// ---------- flash attention v3: LDS-staged K/V, double-buffered prefetch ----------
// block = (q-tile 64, h, b); 4 waves x 16 q-rows. K/V tiles staged once per
// block via global_load_lds (swizzled source, linear dest); fragments read as
// conflict-free swizzled ds_read_b128.
__global__ __launch_bounds__(256, 3) void flash_attn(const u16* __restrict__ Q,
                                                     const u16* __restrict__ K,
                                                     const u16* __restrict__ Vt,
                                                     const u64* __restrict__ Mb64,
                                                     u16* __restrict__ ctx) {
  __shared__ __align__(16) u16 Ksh[2][64][64];  // [buf][kv][d]   chunk-swizzled
  __shared__ __align__(16) u16 Vsh[2][64][64];  // [buf][d][kv]   chunk-swizzled
  __shared__ __align__(16) u16 P[4][16][72];    // per-wave P, stride 144B

  const int tid = threadIdx.x, w = tid >> 6, lane = tid & 63;
  const int r16 = lane & 15, g = lane >> 4;
  const int b = blockIdx.z, h = blockIdx.y;
  const int q0 = blockIdx.x * 64 + w * 16;
  const u16* Qb = Q + ((size_t)(b * 16 + h) << 17);
  const u16* Kb = K + ((size_t)(b * 16 + h) << 17);
  const u16* Vb = Vt + ((size_t)(b * 16 + h) << 17);
  const u64* Mrow = Mb64 + ((size_t)(b * 2048 + q0 + r16) << 5);  // 32 u64 per row
  u16* Pw = &P[w][0][0];

  // stage one 64-kv tile of K and V: 2 chunks each per thread.
  // LDS dest linear (ch*16); global source chunk pre-swizzled: k16 ^ (row&7).
  const int srow = tid >> 3, sk16 = tid & 7;          // ch = i*256+tid -> row = i*32+srow
#define STAGE(buf, kv0)                                                                   \
  {                                                                                       \
    _Pragma("unroll") for (int i = 0; i < 2; i++) {                                       \
      int row = i * 32 + srow;                                                            \
      int sc = sk16 ^ (row & 7);                                                          \
      gload16(Kb + (((size_t)((kv0) + row)) << 6) + sc * 8,                               \
              (char*)&Ksh[buf][0][0] + (i * 256 + tid) * 16);                             \
      gload16(Vb + (((size_t)row) << 11) + (kv0) + sc * 8,                                \
              (char*)&Vsh[buf][0][0] + (i * 256 + tid) * 16);                             \
    }                                                                                     \
  }

  // Q as B-fragment: lane r16 <-> q-col, elems d = c*32+g*8..+7
  s16x8 aq[2];
#pragma unroll
  for (int c = 0; c < 2; c++) aq[c] = *(const s16x8*)(Qb + ((q0 + r16) << 6) + c * 32 + g * 8);

  const f32x4 vz = {0.f, 0.f, 0.f, 0.f};
  f32x4 o[4];
#pragma unroll
  for (int i = 0; i < 4; i++) o[i] = vz;
  float rs = 0.f;                                // per-lane partial row-sum (q = r16)
  const float C2 = 0.125f * 1.44269504088896f;   // scale * log2(e)

  STAGE(0, 0);
  __syncthreads();                               // drains vmcnt -> buf0 ready
  u64 mcur = Mrow[0];

  for (int t = 0; t < 32; t++) {
    const int cur = t & 1;
    if (t < 31) STAGE(cur ^ 1, (t + 1) * 64);    // async prefetch next tile
    u64 mnext = (t < 31) ? Mrow[t + 1] : 0;

    u64 m = mcur >> (g * 4);                     // lane's bits at nt*16 offsets
    u32 mlo = (u32)m, mhi = (u32)(m >> 32);

    // S^T = K @ Q^T : s_[nt][ri] = score(q=r16, k=t*64 + nt*16 + g*4 + ri)
    f32x4 s_[4];
#pragma unroll
    for (int nt = 0; nt < 4; nt++) s_[nt] = vz;
#pragma unroll
    for (int c = 0; c < 2; c++) {
#pragma unroll
      for (int nt = 0; nt < 4; nt++) {
        s16x8 ak = *(const s16x8*)((char*)&Ksh[cur][0][0] + (nt * 16 + r16) * 128 +
                                   (((c * 4 + g) ^ (r16 & 7)) << 4));
        s_[nt] = MFMA(ak, aq[c], s_[nt]);
      }
    }

    // p = exp2(s*C2) * maskbit ; per-lane row-sum; pack bf16 pairs into P
#pragma unroll
    for (int nt = 0; nt < 4; nt++) {
      u32 word = (nt < 2) ? mlo : mhi;
      u32 sh = (nt & 1) << 4;
      float e0 = exp2fast(s_[nt][0] * C2) * (float)((word >> (sh + 0)) & 1);
      float e1 = exp2fast(s_[nt][1] * C2) * (float)((word >> (sh + 1)) & 1);
      float e2 = exp2fast(s_[nt][2] * C2) * (float)((word >> (sh + 2)) & 1);
      float e3 = exp2fast(s_[nt][3] * C2) * (float)((word >> (sh + 3)) & 1);
      rs += (e0 + e1) + (e2 + e3);
      u32 pk0, pk1;
      asm("v_cvt_pk_bf16_f32 %0, %1, %2" : "=v"(pk0) : "v"(e0), "v"(e1));
      asm("v_cvt_pk_bf16_f32 %0, %1, %2" : "=v"(pk1) : "v"(e2), "v"(e3));
      uint2 pr; pr.x = pk0; pr.y = pk1;
      *(uint2*)((char*)Pw + r16 * 144 + nt * 32 + g * 8) = pr;   // P[q=r16][k=nt*16+g*4..]
    }
    asm volatile("" ::: "memory");               // same-wave LDS write -> read ordering

    // PV: o[nt_d] += P(A-frag) @ Vt(B-frag from LDS, swizzled)
#pragma unroll
    for (int c = 0; c < 2; c++) {
      s16x8 pa = *(const s16x8*)((char*)Pw + r16 * 144 + c * 64 + g * 16);
#pragma unroll
      for (int nt = 0; nt < 4; nt++) {
        s16x8 bv = *(const s16x8*)((char*)&Vsh[cur][0][0] + (nt * 16 + r16) * 128 +
                                   (((c * 4 + g) ^ (r16 & 7)) << 4));
        o[nt] = MFMA(pa, bv, o[nt]);
      }
    }
    mcur = mnext;
    __syncthreads();                             // staged tile ready; cur buf free
  }
#undef STAGE

  // final row-sum reduce across g-groups
  rs += __shfl_xor(rs, 16, 64);
  rs += __shfl_xor(rs, 32, 64);
  float inv = 1.f / rs;                          // valid for q = r16 on every lane
  float invq[4];
#pragma unroll
  for (int ri = 0; ri < 4; ri++) invq[ri] = __shfl(inv, g * 4 + ri, 64);  // q = g*4+ri

  // o[nt][ri] = ctx[q=g*4+ri][d=nt*16+r16]; write ctx bf16 [B*S][1024]
#pragma unroll
  for (int nt = 0; nt < 4; nt++) {
    int col = (h << 6) + nt * 16 + r16;
#pragma unroll
    for (int ri = 0; ri < 4; ri++) {
      int row = (b << 11) + q0 + g * 4 + ri;
      ctx[((size_t)row << 10) + col] = f2bf(o[nt][ri] * invq[ri]);
    }
  }
}

// ---------- host ----------
extern "C" void kernel_launch(void* const* d_in, const int* in_sizes, int n_in,
                              void* d_out, int out_size, void* d_ws, size_t ws_size,
                              hipStream_t stream) {
  const float* query = (const float*)d_in[0];
  const float* key_  = (const float*)d_in[1];
  const float* value = (const float*)d_in[2];
  const int*   mask  = (const int*)d_in[3];
  const float* Wq = (const float*)d_in[4];
  const float* bq = (const float*)d_in[5];
  const float* Wk = (const float*)d_in[6];
  const float* bk = (const float*)d_in[7];
  const float* Wv = (const float*)d_in[8];
  const float* bv = (const float*)d_in[9];
  const float* Wo = (const float*)d_in[10];
  const float* bo = (const float*)d_in[11];

  const size_t MB = 1048576;
  char* ws = (char*)d_ws;
  u16* Xq  = (u16*)(ws + 0 * MB);
  u16* Xk  = (u16*)(ws + 8 * MB);
  u16* Xv  = (u16*)(ws + 16 * MB);
  u16* WqT = (u16*)(ws + 24 * MB);
  u16* WkT = (u16*)(ws + 26 * MB);
  u16* WvT = (u16*)(ws + 28 * MB);
  u16* WoT = (u16*)(ws + 30 * MB);
  u16* Qd  = (u16*)(ws + 32 * MB);
  u16* Kd  = (u16*)(ws + 40 * MB);
  u16* Vtd = (u16*)(ws + 48 * MB);
  u16* ctx = (u16*)(ws + 56 * MB);
  u64* Mb  = (u64*)(ws + 72 * MB);   // 1 MB bitmask

  cvt_bf16<<<2048, 256, 0, stream>>>(query, Xq, 524288);
  cvt_bf16<<<2048, 256, 0, stream>>>(key_,  Xk, 524288);
  cvt_bf16<<<2048, 256, 0, stream>>>(value, Xv, 524288);
  mask_bits<<<32768, 256, 0, stream>>>(mask, Mb);

  dim3 tb(32, 8);
  transpose_w_k<<<dim3(32, 32), tb, 0, stream>>>(Wq, WqT);
  transpose_w_k<<<dim3(32, 32), tb, 0, stream>>>(Wk, WkT);
  transpose_w_k<<<dim3(32, 32), tb, 0, stream>>>(Wv, WvT);
  transpose_w_k<<<dim3(32, 32), tb, 0, stream>>>(Wo, WoT);

  proj_gemm<<<dim3(8, 32, 3), 256, 0, stream>>>(Xq, Xk, Xv, WqT, WkT, WvT, bq, bk, bv,
                                                Qd, Kd, Vtd);
  flash_attn<<<dim3(32, 16, 2), 256, 0, stream>>>(Qd, Kd, Vtd, Mb, ctx);
  out_gemm<<<dim3(8, 64), 256, 0, stream>>>(ctx, WoT, bo, (float*)d_out);
}

// Round 4
// 194.907 us; speedup vs baseline: 1.8855x; 1.0612x over previous
//
#include <hip/hip_runtime.h>

typedef __attribute__((ext_vector_type(8))) short s16x8;
typedef __attribute__((ext_vector_type(4))) float f32x4;
typedef unsigned short u16;
typedef unsigned int u32;
typedef unsigned long long u64;

// ---------- helpers ----------
__device__ __forceinline__ u16 f2bf(float f) {            // RNE f32 -> bf16
  u32 u = __builtin_bit_cast(u32, f);
  u += 0x7fff + ((u >> 16) & 1);
  return (u16)(u >> 16);
}

__device__ __forceinline__ float exp2fast(float x) {
#if __has_builtin(__builtin_amdgcn_exp2f)
  return __builtin_amdgcn_exp2f(x);
#else
  return __expf(x * 0.6931471805599453f);
#endif
}

__device__ __forceinline__ void gload16(const void* g, void* l) {
  __builtin_amdgcn_global_load_lds((const __attribute__((address_space(1))) u32*)g,
                                   (__attribute__((address_space(3))) u32*)l, 16, 0, 0);
}

#define MFMA(a, b, c) __builtin_amdgcn_mfma_f32_16x16x32_bf16((a), (b), (c), 0, 0, 0)

// scale * log2(e), folded into Q at projection time
#define QSCALE 0.18033688011112042f

// ---------- fp32 -> bf16 convert, 3 tensors fused (8 elems/thread) ----------
__global__ __launch_bounds__(256) void cvt_bf16_3(const float* __restrict__ q,
                                                  const float* __restrict__ k,
                                                  const float* __restrict__ v,
                                                  u16* __restrict__ oq, u16* __restrict__ ok,
                                                  u16* __restrict__ ov) {
  int z = blockIdx.y;
  const float* src = (z == 0) ? q : (z == 1) ? k : v;
  u16* dst = (z == 0) ? oq : (z == 1) ? ok : ov;
  int i = blockIdx.x * 256 + threadIdx.x;
  const float4* s4 = (const float4*)src;
  float4 a = s4[2 * i], b = s4[2 * i + 1];
  uint4 o;
  o.x = (u32)f2bf(a.x) | ((u32)f2bf(a.y) << 16);
  o.y = (u32)f2bf(a.z) | ((u32)f2bf(a.w) << 16);
  o.z = (u32)f2bf(b.x) | ((u32)f2bf(b.y) << 16);
  o.w = (u32)f2bf(b.z) | ((u32)f2bf(b.w) << 16);
  ((uint4*)dst)[i] = o;
}

// ---------- mask int32 [B,S,S] -> bitmask u64 [B,S,S/64] ----------
__global__ __launch_bounds__(256) void mask_bits(const int* __restrict__ mask,
                                                 u64* __restrict__ mb) {
  int wi = (blockIdx.x * 256 + threadIdx.x) >> 6;   // u64 index, one wave each
  int lane = threadIdx.x & 63;
  u64 bits = __ballot(mask[((size_t)wi << 6) + lane] != 0);
  if (lane == 0) mb[wi] = bits;
}

// ---------- 4x W [1024][1024] f32 -> WT [1024][1024] bf16, fused ----------
__global__ __launch_bounds__(256) void transpose_w4(const float* __restrict__ W0,
                                                    const float* __restrict__ W1,
                                                    const float* __restrict__ W2,
                                                    const float* __restrict__ W3,
                                                    u16* __restrict__ T0, u16* __restrict__ T1,
                                                    u16* __restrict__ T2, u16* __restrict__ T3) {
  int z = blockIdx.z;
  const float* W = (z == 0) ? W0 : (z == 1) ? W1 : (z == 2) ? W2 : W3;
  u16* WT = (z == 0) ? T0 : (z == 1) ? T1 : (z == 2) ? T2 : T3;
  __shared__ float t[32][33];
  int tx = threadIdx.x, ty = threadIdx.y;
  int n = blockIdx.x * 32 + tx;
#pragma unroll
  for (int j = 0; j < 4; j++) {
    int k = blockIdx.y * 32 + ty + 8 * j;
    t[ty + 8 * j][tx] = W[(size_t)k * 1024 + n];
  }
  __syncthreads();
  int k = blockIdx.y * 32 + tx;
#pragma unroll
  for (int j = 0; j < 4; j++) {
    int n2 = blockIdx.x * 32 + ty + 8 * j;
    WT[(size_t)n2 * 1024 + k] = f2bf(t[tx][ty + 8 * j]);
  }
}

// ---------- shared GEMM core: C[BMxBN] = A[m0..][K=1024] * BT[n0..][K=1024]^T ----------
template <int BM, int BN>
__device__ __forceinline__ void gemm_core(const u16* __restrict__ A, const u16* __restrict__ BT,
                                          int m0, int n0, u16* Ash, u16* Bsh,
                                          f32x4 (&acc)[BM / 32][BN / 32]) {
  constexpr int MF = BM / 32, NF = BN / 32;
  const int tid = threadIdx.x;
  const int lane = tid & 63, wid = tid >> 6;
  const int r16 = lane & 15, g = lane >> 4;
  const int wm = wid >> 1, wn = wid & 1;
  const f32x4 vz = {0.f, 0.f, 0.f, 0.f};
#pragma unroll
  for (int mf = 0; mf < MF; mf++)
#pragma unroll
    for (int nf = 0; nf < NF; nf++) acc[mf][nf] = vz;

  for (int k0 = 0; k0 < 1024; k0 += 64) {
#pragma unroll
    for (int i = 0; i < BM / 32; i++) {
      int ch = i * 256 + tid;
      gload16((const char*)A + (((size_t)(m0 + (ch >> 3)) << 10) + k0 + ((ch & 7) << 3)) * 2,
              (char*)Ash + ch * 16);
    }
#pragma unroll
    for (int i = 0; i < BN / 32; i++) {
      int ch = i * 256 + tid;
      gload16((const char*)BT + (((size_t)(n0 + (ch >> 3)) << 10) + k0 + ((ch & 7) << 3)) * 2,
              (char*)Bsh + ch * 16);
    }
    __syncthreads();
#pragma unroll
    for (int kk = 0; kk < 2; kk++) {
      s16x8 af[MF], bfr[NF];
#pragma unroll
      for (int mf = 0; mf < MF; mf++)
        af[mf] = *(const s16x8*)(Ash + ((wm * (BM / 2) + mf * 16 + r16) << 6) + kk * 32 + g * 8);
#pragma unroll
      for (int nf = 0; nf < NF; nf++)
        bfr[nf] = *(const s16x8*)(Bsh + ((wn * (BN / 2) + nf * 16 + r16) << 6) + kk * 32 + g * 8);
#pragma unroll
      for (int mf = 0; mf < MF; mf++)
#pragma unroll
        for (int nf = 0; nf < NF; nf++) acc[mf][nf] = MFMA(af[mf], bfr[nf], acc[mf][nf]);
    }
    __syncthreads();
  }
}

// ---------- fused QKV projection: z=0 Q (pre-scaled), z=1 K, z=2 V (transposed) ----------
__global__ __launch_bounds__(256) void proj_gemm(
    const u16* __restrict__ Xq, const u16* __restrict__ Xk, const u16* __restrict__ Xv,
    const u16* __restrict__ WqT, const u16* __restrict__ WkT, const u16* __restrict__ WvT,
    const float* __restrict__ bq, const float* __restrict__ bk, const float* __restrict__ bv,
    u16* __restrict__ Qo, u16* __restrict__ Ko, u16* __restrict__ Vto) {
  __shared__ u16 Ash[128 * 64], Bsh[128 * 64];
  const int z = blockIdx.z;
  const u16* A = (z == 0) ? Xq : (z == 1) ? Xk : Xv;
  const u16* BT = (z == 0) ? WqT : (z == 1) ? WkT : WvT;
  const float* bias = (z == 0) ? bq : (z == 1) ? bk : bv;
  u16* O = (z == 0) ? Qo : (z == 1) ? Ko : Vto;
  const float sc = (z == 0) ? QSCALE : 1.0f;
  const int m0 = blockIdx.y * 128, n0 = blockIdx.x * 128;
  f32x4 acc[4][4];
  gemm_core<128, 128>(A, BT, m0, n0, Ash, Bsh, acc);
  const int tid = threadIdx.x, lane = tid & 63, wid = tid >> 6;
  const int r16 = lane & 15, g = lane >> 4, wm = wid >> 1, wn = wid & 1;
#pragma unroll
  for (int nf = 0; nf < 4; nf++) {
    int col = n0 + wn * 64 + nf * 16 + r16;
    float bb = bias[col];
    int h = col >> 6, d = col & 63;
#pragma unroll
    for (int mf = 0; mf < 4; mf++) {
#pragma unroll
      for (int ri = 0; ri < 4; ri++) {
        int row = m0 + wm * 64 + mf * 16 + g * 4 + ri;
        int b_ = row >> 11, s_ = row & 2047;
        u16 val = f2bf((acc[mf][nf][ri] + bb) * sc);
        if (z < 2)
          O[((((size_t)b_ * 16 + h) * 2048 + s_) << 6) + d] = val;     // [B,H,S,64]
        else
          O[((((size_t)b_ * 16 + h) * 64 + d) << 11) + s_] = val;     // [B,H,64,S]
      }
    }
  }
}

// ---------- output projection: out = ctx @ WoT^T + bo (fp32) ----------
__global__ __launch_bounds__(256) void out_gemm(const u16* __restrict__ ctx,
                                                const u16* __restrict__ WoT,
                                                const float* __restrict__ bo,
                                                float* __restrict__ out) {
  __shared__ u16 Ash[64 * 64], Bsh[128 * 64];
  const int m0 = blockIdx.y * 64, n0 = blockIdx.x * 128;
  f32x4 acc[2][4];
  gemm_core<64, 128>(ctx, WoT, m0, n0, Ash, Bsh, acc);
  const int tid = threadIdx.x, lane = tid & 63, wid = tid >> 6;
  const int r16 = lane & 15, g = lane >> 4, wm = wid >> 1, wn = wid & 1;
#pragma unroll
  for (int nf = 0; nf < 4; nf++) {
    int col = n0 + wn * 64 + nf * 16 + r16;
    float bb = bo[col];
#pragma unroll
    for (int mf = 0; mf < 2; mf++) {
#pragma unroll
      for (int ri = 0; ri < 4; ri++) {
        int row = m0 + wm * 32 + mf * 16 + g * 4 + ri;
        out[((size_t)row << 10) + col] = acc[mf][nf][ri] + bb;
      }
    }
  }
}

// ---------- flash attention v4: counted-vmcnt pipeline, ones-MFMA row-sum ----------
// block = (q-tile 64, h, b); 4 waves x 16 q-rows. Per tile: batch = 4 gload_lds
// + 1 mask u64 = 5 VMEM, pinned by "memory" asm boundaries. Stage distance 2,
// wait vmcnt(5) (never 0 mid-loop), raw s_barrier x2 per tile.
__global__ __launch_bounds__(256, 3) void flash_attn(const u16* __restrict__ Q,
                                                     const u16* __restrict__ K,
                                                     const u16* __restrict__ Vt,
                                                     const u64* __restrict__ Mb64,
                                                     u16* __restrict__ ctx) {
  __shared__ __align__(16) u16 Ksh[2][64][64];  // [buf][kv][d]   chunk-swizzled
  __shared__ __align__(16) u16 Vsh[2][64][64];  // [buf][d][kv]   chunk-swizzled
  __shared__ __align__(16) u16 P[4][16][72];    // per-wave P, stride 144B

  const int tid = threadIdx.x, w = tid >> 6, lane = tid & 63;
  const int r16 = lane & 15, g = lane >> 4;
  const int b = blockIdx.z, h = blockIdx.y;
  const int q0 = blockIdx.x * 64 + w * 16;
  const u16* Qb = Q + ((size_t)(b * 16 + h) << 17);
  const u16* Kb = K + ((size_t)(b * 16 + h) << 17);
  const u16* Vb = Vt + ((size_t)(b * 16 + h) << 17);
  const u64* Mrow = Mb64 + ((size_t)(b * 2048 + q0 + r16) << 5);  // 32 u64 per row
  u16* Pw = &P[w][0][0];

  const int srow = tid >> 3, sk16 = tid & 7;
#define STAGE(buf, kv0)                                                                   \
  {                                                                                       \
    _Pragma("unroll") for (int i = 0; i < 2; i++) {                                       \
      int row = i * 32 + srow;                                                            \
      int sc = sk16 ^ (row & 7);                                                          \
      gload16(Kb + (((size_t)((kv0) + row)) << 6) + sc * 8,                               \
              (char*)&Ksh[buf][0][0] + (i * 256 + tid) * 16);                             \
      gload16(Vb + (((size_t)row) << 11) + (kv0) + sc * 8,                                \
              (char*)&Vsh[buf][0][0] + (i * 256 + tid) * 16);                             \
    }                                                                                     \
  }

  // Q as B-fragment (pre-scaled by QSCALE at projection)
  s16x8 aq[2];
#pragma unroll
  for (int c = 0; c < 2; c++) aq[c] = *(const s16x8*)(Qb + ((q0 + r16) << 6) + c * 32 + g * 8);
  asm volatile("" ::: "memory");   // pin: aq loads before batch0
  STAGE(0, 0);
  u64 mcur = Mrow[0];
  asm volatile("" ::: "memory");   // pin: batch0 before batch1
  STAGE(1, 64);
  u64 mnext = Mrow[1];
  asm volatile("" ::: "memory");

  s16x8 vones;
#pragma unroll
  for (int j = 0; j < 8; j++) vones[j] = (short)0x3F80;  // bf16 1.0

  const f32x4 vz = {0.f, 0.f, 0.f, 0.f};
  f32x4 o[4], o4 = vz;
#pragma unroll
  for (int i = 0; i < 4; i++) o[i] = vz;

  for (int t = 0; t < 32; t++) {
    const int cur = t & 1;
    // batch(t) drained; batch(t+1) allowed to stay in flight
    if (t == 31) {
      asm volatile("s_waitcnt vmcnt(0)" ::: "memory");
    } else {
      asm volatile("s_waitcnt vmcnt(5)" ::: "memory");
    }
    asm volatile("s_barrier" ::: "memory");          // all waves: buf(cur) ready

    u64 m = mcur >> (g * 4);
    u32 mlo = (u32)m, mhi = (u32)(m >> 32);

    // S^T = K @ Q^T : s_[nt][ri] = score(q=r16, k=t*64 + nt*16 + g*4 + ri), pre-scaled
    f32x4 s_[4];
#pragma unroll
    for (int nt = 0; nt < 4; nt++) s_[nt] = vz;
    __builtin_amdgcn_s_setprio(1);
#pragma unroll
    for (int c = 0; c < 2; c++) {
#pragma unroll
      for (int nt = 0; nt < 4; nt++) {
        s16x8 ak = *(const s16x8*)((char*)&Ksh[cur][0][0] + (nt * 16 + r16) * 128 +
                                   (((c * 4 + g) ^ (r16 & 7)) << 4));
        s_[nt] = MFMA(ak, aq[c], s_[nt]);
      }
    }
    __builtin_amdgcn_s_setprio(0);

    // p = exp2(s) * maskbit ; pack bf16 pairs into P (row-sum folded into PV)
#pragma unroll
    for (int nt = 0; nt < 4; nt++) {
      u32 word = (nt < 2) ? mlo : mhi;
      u32 sh = (nt & 1) << 4;
      float e0 = exp2fast(s_[nt][0]) * (float)((word >> (sh + 0)) & 1);
      float e1 = exp2fast(s_[nt][1]) * (float)((word >> (sh + 1)) & 1);
      float e2 = exp2fast(s_[nt][2]) * (float)((word >> (sh + 2)) & 1);
      float e3 = exp2fast(s_[nt][3]) * (float)((word >> (sh + 3)) & 1);
      u32 pk0, pk1;
      asm("v_cvt_pk_bf16_f32 %0, %1, %2" : "=v"(pk0) : "v"(e0), "v"(e1));
      asm("v_cvt_pk_bf16_f32 %0, %1, %2" : "=v"(pk1) : "v"(e2), "v"(e3));
      uint2 pr; pr.x = pk0; pr.y = pk1;
      *(uint2*)((char*)Pw + r16 * 144 + nt * 32 + g * 8) = pr;   // P[q=r16][k=nt*16+g*4..]
    }
    asm volatile("" ::: "memory");               // same-wave LDS write -> read ordering

    // PV: o[nt_d] += P @ V ; o4 += P @ ones (softmax denominator, right layout)
    __builtin_amdgcn_s_setprio(1);
#pragma unroll
    for (int c = 0; c < 2; c++) {
      s16x8 pa = *(const s16x8*)((char*)Pw + r16 * 144 + c * 64 + g * 16);
#pragma unroll
      for (int nt = 0; nt < 4; nt++) {
        s16x8 bv = *(const s16x8*)((char*)&Vsh[cur][0][0] + (nt * 16 + r16) * 128 +
                                   (((c * 4 + g) ^ (r16 & 7)) << 4));
        o[nt] = MFMA(pa, bv, o[nt]);
      }
      o4 = MFMA(pa, vones, o4);
    }
    __builtin_amdgcn_s_setprio(0);

    asm volatile("s_barrier" ::: "memory");      // all waves done reading buf(cur)
    u64 mnew = 0;
    if (t + 2 < 32) {                            // stage tile t+2 into buf(cur)
      STAGE(cur, (t + 2) * 64);
      mnew = Mrow[t + 2];
    }
    mcur = mnext;
    mnext = mnew;
  }
#undef STAGE

  // o4[ri] = rowsum for q = g*4+ri (all cols equal) -> direct normalization
  float invq[4];
#pragma unroll
  for (int ri = 0; ri < 4; ri++) invq[ri] = 1.f / o4[ri];

  // o[nt][ri] = ctx[q=g*4+ri][d=nt*16+r16]; write ctx bf16 [B*S][1024]
#pragma unroll
  for (int nt = 0; nt < 4; nt++) {
    int col = (h << 6) + nt * 16 + r16;
#pragma unroll
    for (int ri = 0; ri < 4; ri++) {
      int row = (b << 11) + q0 + g * 4 + ri;
      ctx[((size_t)row << 10) + col] = f2bf(o[nt][ri] * invq[ri]);
    }
  }
}

// ---------- host ----------
extern "C" void kernel_launch(void* const* d_in, const int* in_sizes, int n_in,
                              void* d_out, int out_size, void* d_ws, size_t ws_size,
                              hipStream_t stream) {
  const float* query = (const float*)d_in[0];
  const float* key_  = (const float*)d_in[1];
  const float* value = (const float*)d_in[2];
  const int*   mask  = (const int*)d_in[3];
  const float* Wq = (const float*)d_in[4];
  const float* bq = (const float*)d_in[5];
  const float* Wk = (const float*)d_in[6];
  const float* bk = (const float*)d_in[7];
  const float* Wv = (const float*)d_in[8];
  const float* bv = (const float*)d_in[9];
  const float* Wo = (const float*)d_in[10];
  const float* bo = (const float*)d_in[11];

  const size_t MB = 1048576;
  char* ws = (char*)d_ws;
  u16* Xq  = (u16*)(ws + 0 * MB);
  u16* Xk  = (u16*)(ws + 8 * MB);
  u16* Xv  = (u16*)(ws + 16 * MB);
  u16* WqT = (u16*)(ws + 24 * MB);
  u16* WkT = (u16*)(ws + 26 * MB);
  u16* WvT = (u16*)(ws + 28 * MB);
  u16* WoT = (u16*)(ws + 30 * MB);
  u16* Qd  = (u16*)(ws + 32 * MB);
  u16* Kd  = (u16*)(ws + 40 * MB);
  u16* Vtd = (u16*)(ws + 48 * MB);
  u16* ctx = (u16*)(ws + 56 * MB);
  u64* Mb  = (u64*)(ws + 72 * MB);   // 1 MB bitmask

  cvt_bf16_3<<<dim3(2048, 3), 256, 0, stream>>>(query, key_, value, Xq, Xk, Xv);
  mask_bits<<<32768, 256, 0, stream>>>(mask, Mb);

  dim3 tb(32, 8);
  transpose_w4<<<dim3(32, 32, 4), tb, 0, stream>>>(Wq, Wk, Wv, Wo, WqT, WkT, WvT, WoT);

  proj_gemm<<<dim3(8, 32, 3), 256, 0, stream>>>(Xq, Xk, Xv, WqT, WkT, WvT, bq, bk, bv,
                                                Qd, Kd, Vtd);
  flash_attn<<<dim3(32, 16, 2), 256, 0, stream>>>(Qd, Kd, Vtd, Mb, ctx);
  out_gemm<<<dim3(8, 64), 256, 0, stream>>>(ctx, WoT, bo, (float*)d_out);
}

// Round 5
// 176.037 us; speedup vs baseline: 2.0876x; 1.1072x over previous
//
#include <hip/hip_runtime.h>

typedef __attribute__((ext_vector_type(8))) short s16x8;
typedef __attribute__((ext_vector_type(4))) float f32x4;
typedef unsigned short u16;
typedef unsigned int u32;
typedef unsigned long long u64;

// ---------- helpers ----------
__device__ __forceinline__ u16 f2bf(float f) {            // RNE f32 -> bf16
  u32 u = __builtin_bit_cast(u32, f);
  u += 0x7fff + ((u >> 16) & 1);
  return (u16)(u >> 16);
}

__device__ __forceinline__ float exp2fast(float x) {
#if __has_builtin(__builtin_amdgcn_exp2f)
  return __builtin_amdgcn_exp2f(x);
#else
  return __expf(x * 0.6931471805599453f);
#endif
}

__device__ __forceinline__ void gload16(const void* g, void* l) {
  __builtin_amdgcn_global_load_lds((const __attribute__((address_space(1))) u32*)g,
                                   (__attribute__((address_space(3))) u32*)l, 16, 0, 0);
}

#define MFMA(a, b, c) __builtin_amdgcn_mfma_f32_16x16x32_bf16((a), (b), (c), 0, 0, 0)

// scale * log2(e), folded into Q at projection time
#define QSCALE 0.18033688011112042f

// ---------- fp32 -> bf16 convert, 3 tensors fused (8 elems/thread) ----------
__global__ __launch_bounds__(256) void cvt_bf16_3(const float* __restrict__ q,
                                                  const float* __restrict__ k,
                                                  const float* __restrict__ v,
                                                  u16* __restrict__ oq, u16* __restrict__ ok,
                                                  u16* __restrict__ ov) {
  int z = blockIdx.y;
  const float* src = (z == 0) ? q : (z == 1) ? k : v;
  u16* dst = (z == 0) ? oq : (z == 1) ? ok : ov;
  int i = blockIdx.x * 256 + threadIdx.x;
  const float4* s4 = (const float4*)src;
  float4 a = s4[2 * i], b = s4[2 * i + 1];
  uint4 o;
  o.x = (u32)f2bf(a.x) | ((u32)f2bf(a.y) << 16);
  o.y = (u32)f2bf(a.z) | ((u32)f2bf(a.w) << 16);
  o.z = (u32)f2bf(b.x) | ((u32)f2bf(b.y) << 16);
  o.w = (u32)f2bf(b.z) | ((u32)f2bf(b.w) << 16);
  ((uint4*)dst)[i] = o;
}

// ---------- mask int32 [B,S,S] -> bitmask u64 [B,S,S/64] ----------
__global__ __launch_bounds__(256) void mask_bits(const int* __restrict__ mask,
                                                 u64* __restrict__ mb) {
  int wi = (blockIdx.x * 256 + threadIdx.x) >> 6;   // u64 index, one wave each
  int lane = threadIdx.x & 63;
  u64 bits = __ballot(mask[((size_t)wi << 6) + lane] != 0);
  if (lane == 0) mb[wi] = bits;
}

// ---------- 4x W [1024][1024] f32 -> WT [1024][1024] bf16, fused ----------
__global__ __launch_bounds__(256) void transpose_w4(const float* __restrict__ W0,
                                                    const float* __restrict__ W1,
                                                    const float* __restrict__ W2,
                                                    const float* __restrict__ W3,
                                                    u16* __restrict__ T0, u16* __restrict__ T1,
                                                    u16* __restrict__ T2, u16* __restrict__ T3) {
  int z = blockIdx.z;
  const float* W = (z == 0) ? W0 : (z == 1) ? W1 : (z == 2) ? W2 : W3;
  u16* WT = (z == 0) ? T0 : (z == 1) ? T1 : (z == 2) ? T2 : T3;
  __shared__ float t[32][33];
  int tx = threadIdx.x, ty = threadIdx.y;
  int n = blockIdx.x * 32 + tx;
#pragma unroll
  for (int j = 0; j < 4; j++) {
    int k = blockIdx.y * 32 + ty + 8 * j;
    t[ty + 8 * j][tx] = W[(size_t)k * 1024 + n];
  }
  __syncthreads();
  int k = blockIdx.y * 32 + tx;
#pragma unroll
  for (int j = 0; j < 4; j++) {
    int n2 = blockIdx.x * 32 + ty + 8 * j;
    WT[(size_t)n2 * 1024 + k] = f2bf(t[tx][ty + 8 * j]);
  }
}

// ---------- shared GEMM core: C[BMxBN] = A[m0..][K=1024] * BT[n0..][K=1024]^T ----------
template <int BM, int BN>
__device__ __forceinline__ void gemm_core(const u16* __restrict__ A, const u16* __restrict__ BT,
                                          int m0, int n0, u16* Ash, u16* Bsh,
                                          f32x4 (&acc)[BM / 32][BN / 32]) {
  constexpr int MF = BM / 32, NF = BN / 32;
  const int tid = threadIdx.x;
  const int lane = tid & 63, wid = tid >> 6;
  const int r16 = lane & 15, g = lane >> 4;
  const int wm = wid >> 1, wn = wid & 1;
  const f32x4 vz = {0.f, 0.f, 0.f, 0.f};
#pragma unroll
  for (int mf = 0; mf < MF; mf++)
#pragma unroll
    for (int nf = 0; nf < NF; nf++) acc[mf][nf] = vz;

  for (int k0 = 0; k0 < 1024; k0 += 64) {
#pragma unroll
    for (int i = 0; i < BM / 32; i++) {
      int ch = i * 256 + tid;
      gload16((const char*)A + (((size_t)(m0 + (ch >> 3)) << 10) + k0 + ((ch & 7) << 3)) * 2,
              (char*)Ash + ch * 16);
    }
#pragma unroll
    for (int i = 0; i < BN / 32; i++) {
      int ch = i * 256 + tid;
      gload16((const char*)BT + (((size_t)(n0 + (ch >> 3)) << 10) + k0 + ((ch & 7) << 3)) * 2,
              (char*)Bsh + ch * 16);
    }
    __syncthreads();
#pragma unroll
    for (int kk = 0; kk < 2; kk++) {
      s16x8 af[MF], bfr[NF];
#pragma unroll
      for (int mf = 0; mf < MF; mf++)
        af[mf] = *(const s16x8*)(Ash + ((wm * (BM / 2) + mf * 16 + r16) << 6) + kk * 32 + g * 8);
#pragma unroll
      for (int nf = 0; nf < NF; nf++)
        bfr[nf] = *(const s16x8*)(Bsh + ((wn * (BN / 2) + nf * 16 + r16) << 6) + kk * 32 + g * 8);
#pragma unroll
      for (int mf = 0; mf < MF; mf++)
#pragma unroll
        for (int nf = 0; nf < NF; nf++) acc[mf][nf] = MFMA(af[mf], bfr[nf], acc[mf][nf]);
    }
    __syncthreads();
  }
}

// ---------- fused QKV projection: z=0 Q (pre-scaled), z=1 K, z=2 V (transposed) ----------
__global__ __launch_bounds__(256) void proj_gemm(
    const u16* __restrict__ Xq, const u16* __restrict__ Xk, const u16* __restrict__ Xv,
    const u16* __restrict__ WqT, const u16* __restrict__ WkT, const u16* __restrict__ WvT,
    const float* __restrict__ bq, const float* __restrict__ bk, const float* __restrict__ bv,
    u16* __restrict__ Qo, u16* __restrict__ Ko, u16* __restrict__ Vto) {
  __shared__ u16 Ash[128 * 64], Bsh[128 * 64];
  const int z = blockIdx.z;
  const u16* A = (z == 0) ? Xq : (z == 1) ? Xk : Xv;
  const u16* BT = (z == 0) ? WqT : (z == 1) ? WkT : WvT;
  const float* bias = (z == 0) ? bq : (z == 1) ? bk : bv;
  u16* O = (z == 0) ? Qo : (z == 1) ? Ko : Vto;
  const float sc = (z == 0) ? QSCALE : 1.0f;
  const int m0 = blockIdx.y * 128, n0 = blockIdx.x * 128;
  f32x4 acc[4][4];
  gemm_core<128, 128>(A, BT, m0, n0, Ash, Bsh, acc);
  const int tid = threadIdx.x, lane = tid & 63, wid = tid >> 6;
  const int r16 = lane & 15, g = lane >> 4, wm = wid >> 1, wn = wid & 1;
#pragma unroll
  for (int nf = 0; nf < 4; nf++) {
    int col = n0 + wn * 64 + nf * 16 + r16;
    float bb = bias[col];
    int h = col >> 6, d = col & 63;
#pragma unroll
    for (int mf = 0; mf < 4; mf++) {
#pragma unroll
      for (int ri = 0; ri < 4; ri++) {
        int row = m0 + wm * 64 + mf * 16 + g * 4 + ri;
        int b_ = row >> 11, s_ = row & 2047;
        u16 val = f2bf((acc[mf][nf][ri] + bb) * sc);
        if (z < 2)
          O[((((size_t)b_ * 16 + h) * 2048 + s_) << 6) + d] = val;     // [B,H,S,64]
        else
          O[((((size_t)b_ * 16 + h) * 64 + d) << 11) + s_] = val;     // [B,H,64,S]
      }
    }
  }
}

// ---------- output projection: out = ctx @ WoT^T + bo (fp32) ----------
__global__ __launch_bounds__(256) void out_gemm(const u16* __restrict__ ctx,
                                                const u16* __restrict__ WoT,
                                                const float* __restrict__ bo,
                                                float* __restrict__ out) {
  __shared__ u16 Ash[64 * 64], Bsh[128 * 64];
  const int m0 = blockIdx.y * 64, n0 = blockIdx.x * 128;
  f32x4 acc[2][4];
  gemm_core<64, 128>(ctx, WoT, m0, n0, Ash, Bsh, acc);
  const int tid = threadIdx.x, lane = tid & 63, wid = tid >> 6;
  const int r16 = lane & 15, g = lane >> 4, wm = wid >> 1, wn = wid & 1;
#pragma unroll
  for (int nf = 0; nf < 4; nf++) {
    int col = n0 + wn * 64 + nf * 16 + r16;
    float bb = bo[col];
#pragma unroll
    for (int mf = 0; mf < 2; mf++) {
#pragma unroll
      for (int ri = 0; ri < 4; ri++) {
        int row = m0 + wm * 32 + mf * 16 + g * 4 + ri;
        out[((size_t)row << 10) + col] = acc[mf][nf][ri] + bb;
      }
    }
  }
}

// ---------- flash attention v5: 32 q/wave (halved LDS traffic/q), counted-vmcnt ----------
// block = (q-tile 128, h, b); 4 waves x 32 q-rows (2 sub-blocks of 16).
// Each K/V fragment read from LDS now feeds 2 MFMAs. Batch = 4 gload_lds +
// 2 mask u64 = 6 VMEM; stage distance 2; wait vmcnt(6) mid-loop (never 0).
__global__ __launch_bounds__(256, 2) void flash_attn(const u16* __restrict__ Q,
                                                     const u16* __restrict__ K,
                                                     const u16* __restrict__ Vt,
                                                     const u64* __restrict__ Mb64,
                                                     u16* __restrict__ ctx) {
  __shared__ __align__(16) u16 Ksh[2][64][64];  // [buf][kv][d]   chunk-swizzled
  __shared__ __align__(16) u16 Vsh[2][64][64];  // [buf][d][kv]   chunk-swizzled
  __shared__ __align__(16) u16 P[4][32][72];    // per-wave P (32 q rows), stride 144B

  const int tid = threadIdx.x, w = tid >> 6, lane = tid & 63;
  const int r16 = lane & 15, g = lane >> 4;
  const int b = blockIdx.z, h = blockIdx.y;
  const int q0 = blockIdx.x * 128 + w * 32;     // wave's 32 q rows
  const u16* Qb = Q + ((size_t)(b * 16 + h) << 17);
  const u16* Kb = K + ((size_t)(b * 16 + h) << 17);
  const u16* Vb = Vt + ((size_t)(b * 16 + h) << 17);
  const u64* Mrow0 = Mb64 + ((size_t)(b * 2048 + q0 + r16) << 5);       // qb=0
  const u64* Mrow1 = Mb64 + ((size_t)(b * 2048 + q0 + 16 + r16) << 5);  // qb=1
  u16* Pw = &P[w][0][0];

  const int srow = tid >> 3, sk16 = tid & 7;
#define STAGE(buf, kv0)                                                                   \
  {                                                                                       \
    _Pragma("unroll") for (int i = 0; i < 2; i++) {                                       \
      int row = i * 32 + srow;                                                            \
      int sc = sk16 ^ (row & 7);                                                          \
      gload16(Kb + (((size_t)((kv0) + row)) << 6) + sc * 8,                               \
              (char*)&Ksh[buf][0][0] + (i * 256 + tid) * 16);                             \
      gload16(Vb + (((size_t)row) << 11) + (kv0) + sc * 8,                                \
              (char*)&Vsh[buf][0][0] + (i * 256 + tid) * 16);                             \
    }                                                                                     \
  }

  // Q as B-fragment (pre-scaled by QSCALE at projection): aq[qb][c]
  s16x8 aq[2][2];
#pragma unroll
  for (int qb = 0; qb < 2; qb++)
#pragma unroll
    for (int c = 0; c < 2; c++)
      aq[qb][c] = *(const s16x8*)(Qb + ((q0 + qb * 16 + r16) << 6) + c * 32 + g * 8);
  asm volatile("" ::: "memory");   // pin: aq loads before batch0
  STAGE(0, 0);
  u64 mcur0 = Mrow0[0], mcur1 = Mrow1[0];
  asm volatile("" ::: "memory");   // pin: batch0 before batch1
  STAGE(1, 64);
  u64 mnext0 = Mrow0[1], mnext1 = Mrow1[1];
  asm volatile("" ::: "memory");

  s16x8 vones;
#pragma unroll
  for (int j = 0; j < 8; j++) vones[j] = (short)0x3F80;  // bf16 1.0

  const f32x4 vz = {0.f, 0.f, 0.f, 0.f};
  f32x4 o[2][4], o4[2];
#pragma unroll
  for (int qb = 0; qb < 2; qb++) {
    o4[qb] = vz;
#pragma unroll
    for (int i = 0; i < 4; i++) o[qb][i] = vz;
  }

  for (int t = 0; t < 32; t++) {
    const int cur = t & 1;
    // batch(t) drained; batch(t+1) stays in flight
    if (t == 31) {
      asm volatile("s_waitcnt vmcnt(0)" ::: "memory");
    } else {
      asm volatile("s_waitcnt vmcnt(6)" ::: "memory");
    }
    asm volatile("s_barrier" ::: "memory");          // all waves: buf(cur) ready

    // S^T = K @ Q^T for both q sub-blocks; each ak read feeds 2 MFMAs
    f32x4 s_[2][4];
#pragma unroll
    for (int qb = 0; qb < 2; qb++)
#pragma unroll
      for (int nt = 0; nt < 4; nt++) s_[qb][nt] = vz;
    __builtin_amdgcn_s_setprio(1);
#pragma unroll
    for (int c = 0; c < 2; c++) {
#pragma unroll
      for (int nt = 0; nt < 4; nt++) {
        s16x8 ak = *(const s16x8*)((char*)&Ksh[cur][0][0] + (nt * 16 + r16) * 128 +
                                   (((c * 4 + g) ^ (r16 & 7)) << 4));
        s_[0][nt] = MFMA(ak, aq[0][c], s_[0][nt]);
        s_[1][nt] = MFMA(ak, aq[1][c], s_[1][nt]);
      }
    }
    __builtin_amdgcn_s_setprio(0);

    // p = exp2(s) * maskbit ; pack bf16 pairs into P rows qb*16+r16
#pragma unroll
    for (int qb = 0; qb < 2; qb++) {
      u64 m = ((qb == 0) ? mcur0 : mcur1) >> (g * 4);
      u32 mlo = (u32)m, mhi = (u32)(m >> 32);
#pragma unroll
      for (int nt = 0; nt < 4; nt++) {
        u32 word = (nt < 2) ? mlo : mhi;
        u32 sh = (nt & 1) << 4;
        float e0 = exp2fast(s_[qb][nt][0]) * (float)((word >> (sh + 0)) & 1);
        float e1 = exp2fast(s_[qb][nt][1]) * (float)((word >> (sh + 1)) & 1);
        float e2 = exp2fast(s_[qb][nt][2]) * (float)((word >> (sh + 2)) & 1);
        float e3 = exp2fast(s_[qb][nt][3]) * (float)((word >> (sh + 3)) & 1);
        u32 pk0, pk1;
        asm("v_cvt_pk_bf16_f32 %0, %1, %2" : "=v"(pk0) : "v"(e0), "v"(e1));
        asm("v_cvt_pk_bf16_f32 %0, %1, %2" : "=v"(pk1) : "v"(e2), "v"(e3));
        uint2 pr; pr.x = pk0; pr.y = pk1;
        *(uint2*)((char*)Pw + (qb * 16 + r16) * 144 + nt * 32 + g * 8) = pr;
      }
    }
    asm volatile("" ::: "memory");               // same-wave LDS write -> read ordering

    // PV: o[qb][nt_d] += P @ V ; o4[qb] += P @ ones; each bv read feeds 2 MFMAs
    __builtin_amdgcn_s_setprio(1);
#pragma unroll
    for (int c = 0; c < 2; c++) {
      s16x8 pa0 = *(const s16x8*)((char*)Pw + r16 * 144 + c * 64 + g * 16);
      s16x8 pa1 = *(const s16x8*)((char*)Pw + (16 + r16) * 144 + c * 64 + g * 16);
#pragma unroll
      for (int nt = 0; nt < 4; nt++) {
        s16x8 bv = *(const s16x8*)((char*)&Vsh[cur][0][0] + (nt * 16 + r16) * 128 +
                                   (((c * 4 + g) ^ (r16 & 7)) << 4));
        o[0][nt] = MFMA(pa0, bv, o[0][nt]);
        o[1][nt] = MFMA(pa1, bv, o[1][nt]);
      }
      o4[0] = MFMA(pa0, vones, o4[0]);
      o4[1] = MFMA(pa1, vones, o4[1]);
    }
    __builtin_amdgcn_s_setprio(0);

    asm volatile("s_barrier" ::: "memory");      // all waves done reading buf(cur)
    u64 mnew0 = 0, mnew1 = 0;
    if (t + 2 < 32) {                            // stage tile t+2 into buf(cur)
      STAGE(cur, (t + 2) * 64);
      mnew0 = Mrow0[t + 2];
      mnew1 = Mrow1[t + 2];
    }
    mcur0 = mnext0; mcur1 = mnext1;
    mnext0 = mnew0; mnext1 = mnew1;
  }
#undef STAGE

  // o4[qb][ri] = rowsum for q = qb*16 + g*4 + ri -> direct normalization, then write
#pragma unroll
  for (int qb = 0; qb < 2; qb++) {
    float invq[4];
#pragma unroll
    for (int ri = 0; ri < 4; ri++) invq[ri] = 1.f / o4[qb][ri];
#pragma unroll
    for (int nt = 0; nt < 4; nt++) {
      int col = (h << 6) + nt * 16 + r16;
#pragma unroll
      for (int ri = 0; ri < 4; ri++) {
        int row = (b << 11) + q0 + qb * 16 + g * 4 + ri;
        ctx[((size_t)row << 10) + col] = f2bf(o[qb][nt][ri] * invq[ri]);
      }
    }
  }
}

// ---------- host ----------
extern "C" void kernel_launch(void* const* d_in, const int* in_sizes, int n_in,
                              void* d_out, int out_size, void* d_ws, size_t ws_size,
                              hipStream_t stream) {
  const float* query = (const float*)d_in[0];
  const float* key_  = (const float*)d_in[1];
  const float* value = (const float*)d_in[2];
  const int*   mask  = (const int*)d_in[3];
  const float* Wq = (const float*)d_in[4];
  const float* bq = (const float*)d_in[5];
  const float* Wk = (const float*)d_in[6];
  const float* bk = (const float*)d_in[7];
  const float* Wv = (const float*)d_in[8];
  const float* bv = (const float*)d_in[9];
  const float* Wo = (const float*)d_in[10];
  const float* bo = (const float*)d_in[11];

  const size_t MB = 1048576;
  char* ws = (char*)d_ws;
  u16* Xq  = (u16*)(ws + 0 * MB);
  u16* Xk  = (u16*)(ws + 8 * MB);
  u16* Xv  = (u16*)(ws + 16 * MB);
  u16* WqT = (u16*)(ws + 24 * MB);
  u16* WkT = (u16*)(ws + 26 * MB);
  u16* WvT = (u16*)(ws + 28 * MB);
  u16* WoT = (u16*)(ws + 30 * MB);
  u16* Qd  = (u16*)(ws + 32 * MB);
  u16* Kd  = (u16*)(ws + 40 * MB);
  u16* Vtd = (u16*)(ws + 48 * MB);
  u16* ctx = (u16*)(ws + 56 * MB);
  u64* Mb  = (u64*)(ws + 72 * MB);   // 1 MB bitmask

  cvt_bf16_3<<<dim3(2048, 3), 256, 0, stream>>>(query, key_, value, Xq, Xk, Xv);
  mask_bits<<<32768, 256, 0, stream>>>(mask, Mb);

  dim3 tb(32, 8);
  transpose_w4<<<dim3(32, 32, 4), tb, 0, stream>>>(Wq, Wk, Wv, Wo, WqT, WkT, WvT, WoT);

  proj_gemm<<<dim3(8, 32, 3), 256, 0, stream>>>(Xq, Xk, Xv, WqT, WkT, WvT, bq, bk, bv,
                                                Qd, Kd, Vtd);
  flash_attn<<<dim3(16, 16, 2), 256, 0, stream>>>(Qd, Kd, Vtd, Mb, ctx);
  out_gemm<<<dim3(8, 64), 256, 0, stream>>>(ctx, WoT, bo, (float*)d_out);
}

// Round 6
// 158.953 us; speedup vs baseline: 2.3119x; 1.1075x over previous
//
#include <hip/hip_runtime.h>

typedef __attribute__((ext_vector_type(8))) short s16x8;
typedef __attribute__((ext_vector_type(4))) float f32x4;
typedef unsigned short u16;
typedef unsigned int u32;
typedef unsigned long long u64;

// ---------- helpers ----------
__device__ __forceinline__ u16 f2bf(float f) {            // RNE f32 -> bf16
  u32 u = __builtin_bit_cast(u32, f);
  u += 0x7fff + ((u >> 16) & 1);
  return (u16)(u >> 16);
}

__device__ __forceinline__ float exp2fast(float x) {
#if __has_builtin(__builtin_amdgcn_exp2f)
  return __builtin_amdgcn_exp2f(x);
#else
  return __expf(x * 0.6931471805599453f);
#endif
}

__device__ __forceinline__ void gload16(const void* g, void* l) {
  __builtin_amdgcn_global_load_lds((const __attribute__((address_space(1))) u32*)g,
                                   (__attribute__((address_space(3))) u32*)l, 16, 0, 0);
}

#define MFMA(a, b, c) __builtin_amdgcn_mfma_f32_16x16x32_bf16((a), (b), (c), 0, 0, 0)

// scale * log2(e), folded into Q at projection time
#define QSCALE 0.18033688011112042f

// ---------- fp32 -> bf16 convert, 3 tensors fused (8 elems/thread) ----------
__global__ __launch_bounds__(256) void cvt_bf16_3(const float* __restrict__ q,
                                                  const float* __restrict__ k,
                                                  const float* __restrict__ v,
                                                  u16* __restrict__ oq, u16* __restrict__ ok,
                                                  u16* __restrict__ ov) {
  int z = blockIdx.y;
  const float* src = (z == 0) ? q : (z == 1) ? k : v;
  u16* dst = (z == 0) ? oq : (z == 1) ? ok : ov;
  int i = blockIdx.x * 256 + threadIdx.x;
  const float4* s4 = (const float4*)src;
  float4 a = s4[2 * i], b = s4[2 * i + 1];
  uint4 o;
  o.x = (u32)f2bf(a.x) | ((u32)f2bf(a.y) << 16);
  o.y = (u32)f2bf(a.z) | ((u32)f2bf(a.w) << 16);
  o.z = (u32)f2bf(b.x) | ((u32)f2bf(b.y) << 16);
  o.w = (u32)f2bf(b.z) | ((u32)f2bf(b.w) << 16);
  ((uint4*)dst)[i] = o;
}

// ---------- mask int32 [B,S,S] -> bitmask u64 [B,S,S/64] ----------
__global__ __launch_bounds__(256) void mask_bits(const int* __restrict__ mask,
                                                 u64* __restrict__ mb) {
  int wi = (blockIdx.x * 256 + threadIdx.x) >> 6;   // u64 index, one wave each
  int lane = threadIdx.x & 63;
  u64 bits = __ballot(mask[((size_t)wi << 6) + lane] != 0);
  if (lane == 0) mb[wi] = bits;
}

// ---------- 4x W [1024][1024] f32 -> WT [1024][1024] bf16, fused ----------
__global__ __launch_bounds__(256) void transpose_w4(const float* __restrict__ W0,
                                                    const float* __restrict__ W1,
                                                    const float* __restrict__ W2,
                                                    const float* __restrict__ W3,
                                                    u16* __restrict__ T0, u16* __restrict__ T1,
                                                    u16* __restrict__ T2, u16* __restrict__ T3) {
  int z = blockIdx.z;
  const float* W = (z == 0) ? W0 : (z == 1) ? W1 : (z == 2) ? W2 : W3;
  u16* WT = (z == 0) ? T0 : (z == 1) ? T1 : (z == 2) ? T2 : T3;
  __shared__ float t[32][33];
  int tx = threadIdx.x, ty = threadIdx.y;
  int n = blockIdx.x * 32 + tx;
#pragma unroll
  for (int j = 0; j < 4; j++) {
    int k = blockIdx.y * 32 + ty + 8 * j;
    t[ty + 8 * j][tx] = W[(size_t)k * 1024 + n];
  }
  __syncthreads();
  int k = blockIdx.y * 32 + tx;
#pragma unroll
  for (int j = 0; j < 4; j++) {
    int n2 = blockIdx.x * 32 + ty + 8 * j;
    WT[(size_t)n2 * 1024 + k] = f2bf(t[tx][ty + 8 * j]);
  }
}

// ---------- pipelined GEMM core: C[BMxBN] = A[m0..][K=1024] * BT[n0..][K=1024]^T ----------
// dist-2 double-buffered staging via global_load_lds, counted vmcnt (never 0
// mid-loop), both-sides XOR chunk swizzle (source pre-swizzled, LDS linear,
// swizzled ds_read) -> 2-way max bank aliasing (free).
template <int BM, int BN>
__device__ __forceinline__ void gemm_core(const u16* __restrict__ A, const u16* __restrict__ BT,
                                          int m0, int n0, u16* Ash, u16* Bsh,
                                          f32x4 (&acc)[BM / 32][BN / 32]) {
  constexpr int MF = BM / 32, NF = BN / 32;
  constexpr int BATCH = BM / 32 + BN / 32;   // gload16 per thread per K-tile
  const int tid = threadIdx.x;
  const int lane = tid & 63, wid = tid >> 6;
  const int r16 = lane & 15, g = lane >> 4;
  const int wm = wid >> 1, wn = wid & 1;
  const int swz = r16 & 7;
  const f32x4 vz = {0.f, 0.f, 0.f, 0.f};
#pragma unroll
  for (int mf = 0; mf < MF; mf++)
#pragma unroll
    for (int nf = 0; nf < NF; nf++) acc[mf][nf] = vz;

  // stage one K-tile (64 wide) into buf: source chunk pre-swizzled, dest linear
  auto stage = [&](int buf, int k0) {
#pragma unroll
    for (int i = 0; i < MF; i++) {
      int ch = i * 256 + tid;
      int row = ch >> 3, sc = (ch & 7) ^ (row & 7);
      gload16(A + (((size_t)(m0 + row)) << 10) + k0 + sc * 8,
              Ash + (size_t)buf * (BM * 64) + ch * 8);
    }
#pragma unroll
    for (int i = 0; i < NF; i++) {
      int ch = i * 256 + tid;
      int row = ch >> 3, sc = (ch & 7) ^ (row & 7);
      gload16(BT + (((size_t)(n0 + row)) << 10) + k0 + sc * 8,
              Bsh + (size_t)buf * (BN * 64) + ch * 8);
    }
  };

  asm volatile("" ::: "memory");
  stage(0, 0);
  asm volatile("" ::: "memory");
  stage(1, 64);
  asm volatile("" ::: "memory");

  for (int t = 0; t < 16; t++) {
    const int cur = t & 1;
    if (t == 15) {
      asm volatile("s_waitcnt vmcnt(0)" ::: "memory");
    } else if constexpr (BATCH == 8) {
      asm volatile("s_waitcnt vmcnt(8)" ::: "memory");
    } else {
      asm volatile("s_waitcnt vmcnt(6)" ::: "memory");
    }
    asm volatile("s_barrier" ::: "memory");      // buf(cur) ready

    const u16* Acur = Ash + (size_t)cur * (BM * 64);
    const u16* Bcur = Bsh + (size_t)cur * (BN * 64);
    __builtin_amdgcn_s_setprio(1);
#pragma unroll
    for (int kk = 0; kk < 2; kk++) {
      const int c = (kk * 4 + g);
      s16x8 af[MF], bfr[NF];
#pragma unroll
      for (int mf = 0; mf < MF; mf++)
        af[mf] = *(const s16x8*)(Acur + ((wm * (BM / 2) + mf * 16 + r16) << 6) +
                                 ((c ^ swz) << 3));
#pragma unroll
      for (int nf = 0; nf < NF; nf++)
        bfr[nf] = *(const s16x8*)(Bcur + ((wn * (BN / 2) + nf * 16 + r16) << 6) +
                                  ((c ^ swz) << 3));
#pragma unroll
      for (int mf = 0; mf < MF; mf++)
#pragma unroll
        for (int nf = 0; nf < NF; nf++) acc[mf][nf] = MFMA(af[mf], bfr[nf], acc[mf][nf]);
    }
    __builtin_amdgcn_s_setprio(0);

    asm volatile("s_barrier" ::: "memory");      // all waves done reading buf(cur)
    if (t + 2 < 16) stage(cur, (t + 2) * 64);    // refill freed buffer
  }
}

// ---------- fused QKV projection: z=0 Q (pre-scaled), z=1 K, z=2 V (transposed) ----------
__global__ __launch_bounds__(256, 2) void proj_gemm(
    const u16* __restrict__ Xq, const u16* __restrict__ Xk, const u16* __restrict__ Xv,
    const u16* __restrict__ WqT, const u16* __restrict__ WkT, const u16* __restrict__ WvT,
    const float* __restrict__ bq, const float* __restrict__ bk, const float* __restrict__ bv,
    u16* __restrict__ Qo, u16* __restrict__ Ko, u16* __restrict__ Vto) {
  __shared__ u16 Ash[2 * 128 * 64], Bsh[2 * 128 * 64];
  const int z = blockIdx.z;
  const u16* A = (z == 0) ? Xq : (z == 1) ? Xk : Xv;
  const u16* BT = (z == 0) ? WqT : (z == 1) ? WkT : WvT;
  const float* bias = (z == 0) ? bq : (z == 1) ? bk : bv;
  u16* O = (z == 0) ? Qo : (z == 1) ? Ko : Vto;
  const float sc = (z == 0) ? QSCALE : 1.0f;
  const int m0 = blockIdx.y * 128, n0 = blockIdx.x * 128;
  f32x4 acc[4][4];
  gemm_core<128, 128>(A, BT, m0, n0, Ash, Bsh, acc);
  const int tid = threadIdx.x, lane = tid & 63, wid = tid >> 6;
  const int r16 = lane & 15, g = lane >> 4, wm = wid >> 1, wn = wid & 1;
#pragma unroll
  for (int nf = 0; nf < 4; nf++) {
    int col = n0 + wn * 64 + nf * 16 + r16;
    float bb = bias[col];
    int h = col >> 6, d = col & 63;
#pragma unroll
    for (int mf = 0; mf < 4; mf++) {
#pragma unroll
      for (int ri = 0; ri < 4; ri++) {
        int row = m0 + wm * 64 + mf * 16 + g * 4 + ri;
        int b_ = row >> 11, s_ = row & 2047;
        u16 val = f2bf((acc[mf][nf][ri] + bb) * sc);
        if (z < 2)
          O[((((size_t)b_ * 16 + h) * 2048 + s_) << 6) + d] = val;     // [B,H,S,64]
        else
          O[((((size_t)b_ * 16 + h) * 64 + d) << 11) + s_] = val;     // [B,H,64,S]
      }
    }
  }
}

// ---------- output projection: out = ctx @ WoT^T + bo (fp32) ----------
__global__ __launch_bounds__(256, 2) void out_gemm(const u16* __restrict__ ctx,
                                                   const u16* __restrict__ WoT,
                                                   const float* __restrict__ bo,
                                                   float* __restrict__ out) {
  __shared__ u16 Ash[2 * 64 * 64], Bsh[2 * 128 * 64];
  const int m0 = blockIdx.y * 64, n0 = blockIdx.x * 128;
  f32x4 acc[2][4];
  gemm_core<64, 128>(ctx, WoT, m0, n0, Ash, Bsh, acc);
  const int tid = threadIdx.x, lane = tid & 63, wid = tid >> 6;
  const int r16 = lane & 15, g = lane >> 4, wm = wid >> 1, wn = wid & 1;
#pragma unroll
  for (int nf = 0; nf < 4; nf++) {
    int col = n0 + wn * 64 + nf * 16 + r16;
    float bb = bo[col];
#pragma unroll
    for (int mf = 0; mf < 2; mf++) {
#pragma unroll
      for (int ri = 0; ri < 4; ri++) {
        int row = m0 + wm * 32 + mf * 16 + g * 4 + ri;
        out[((size_t)row << 10) + col] = acc[mf][nf][ri] + bb;
      }
    }
  }
}

// ---------- flash attention v5: 32 q/wave, counted-vmcnt pipeline ----------
__global__ __launch_bounds__(256, 2) void flash_attn(const u16* __restrict__ Q,
                                                     const u16* __restrict__ K,
                                                     const u16* __restrict__ Vt,
                                                     const u64* __restrict__ Mb64,
                                                     u16* __restrict__ ctx) {
  __shared__ __align__(16) u16 Ksh[2][64][64];  // [buf][kv][d]   chunk-swizzled
  __shared__ __align__(16) u16 Vsh[2][64][64];  // [buf][d][kv]   chunk-swizzled
  __shared__ __align__(16) u16 P[4][32][72];    // per-wave P (32 q rows), stride 144B

  const int tid = threadIdx.x, w = tid >> 6, lane = tid & 63;
  const int r16 = lane & 15, g = lane >> 4;
  const int b = blockIdx.z, h = blockIdx.y;
  const int q0 = blockIdx.x * 128 + w * 32;     // wave's 32 q rows
  const u16* Qb = Q + ((size_t)(b * 16 + h) << 17);
  const u16* Kb = K + ((size_t)(b * 16 + h) << 17);
  const u16* Vb = Vt + ((size_t)(b * 16 + h) << 17);
  const u64* Mrow0 = Mb64 + ((size_t)(b * 2048 + q0 + r16) << 5);       // qb=0
  const u64* Mrow1 = Mb64 + ((size_t)(b * 2048 + q0 + 16 + r16) << 5);  // qb=1
  u16* Pw = &P[w][0][0];

  const int srow = tid >> 3, sk16 = tid & 7;
#define STAGE(buf, kv0)                                                                   \
  {                                                                                       \
    _Pragma("unroll") for (int i = 0; i < 2; i++) {                                       \
      int row = i * 32 + srow;                                                            \
      int sc = sk16 ^ (row & 7);                                                          \
      gload16(Kb + (((size_t)((kv0) + row)) << 6) + sc * 8,                               \
              (char*)&Ksh[buf][0][0] + (i * 256 + tid) * 16);                             \
      gload16(Vb + (((size_t)row) << 11) + (kv0) + sc * 8,                                \
              (char*)&Vsh[buf][0][0] + (i * 256 + tid) * 16);                             \
    }                                                                                     \
  }

  // Q as B-fragment (pre-scaled by QSCALE at projection): aq[qb][c]
  s16x8 aq[2][2];
#pragma unroll
  for (int qb = 0; qb < 2; qb++)
#pragma unroll
    for (int c = 0; c < 2; c++)
      aq[qb][c] = *(const s16x8*)(Qb + ((q0 + qb * 16 + r16) << 6) + c * 32 + g * 8);
  asm volatile("" ::: "memory");   // pin: aq loads before batch0
  STAGE(0, 0);
  u64 mcur0 = Mrow0[0], mcur1 = Mrow1[0];
  asm volatile("" ::: "memory");   // pin: batch0 before batch1
  STAGE(1, 64);
  u64 mnext0 = Mrow0[1], mnext1 = Mrow1[1];
  asm volatile("" ::: "memory");

  s16x8 vones;
#pragma unroll
  for (int j = 0; j < 8; j++) vones[j] = (short)0x3F80;  // bf16 1.0

  const f32x4 vz = {0.f, 0.f, 0.f, 0.f};
  f32x4 o[2][4], o4[2];
#pragma unroll
  for (int qb = 0; qb < 2; qb++) {
    o4[qb] = vz;
#pragma unroll
    for (int i = 0; i < 4; i++) o[qb][i] = vz;
  }

  for (int t = 0; t < 32; t++) {
    const int cur = t & 1;
    if (t == 31) {
      asm volatile("s_waitcnt vmcnt(0)" ::: "memory");
    } else {
      asm volatile("s_waitcnt vmcnt(6)" ::: "memory");
    }
    asm volatile("s_barrier" ::: "memory");          // all waves: buf(cur) ready

    // S^T = K @ Q^T for both q sub-blocks; each ak read feeds 2 MFMAs
    f32x4 s_[2][4];
#pragma unroll
    for (int qb = 0; qb < 2; qb++)
#pragma unroll
      for (int nt = 0; nt < 4; nt++) s_[qb][nt] = vz;
    __builtin_amdgcn_s_setprio(1);
#pragma unroll
    for (int c = 0; c < 2; c++) {
#pragma unroll
      for (int nt = 0; nt < 4; nt++) {
        s16x8 ak = *(const s16x8*)((char*)&Ksh[cur][0][0] + (nt * 16 + r16) * 128 +
                                   (((c * 4 + g) ^ (r16 & 7)) << 4));
        s_[0][nt] = MFMA(ak, aq[0][c], s_[0][nt]);
        s_[1][nt] = MFMA(ak, aq[1][c], s_[1][nt]);
      }
    }
    __builtin_amdgcn_s_setprio(0);

    // p = exp2(s) * maskbit ; pack bf16 pairs into P rows qb*16+r16
#pragma unroll
    for (int qb = 0; qb < 2; qb++) {
      u64 m = ((qb == 0) ? mcur0 : mcur1) >> (g * 4);
      u32 mlo = (u32)m, mhi = (u32)(m >> 32);
#pragma unroll
      for (int nt = 0; nt < 4; nt++) {
        u32 word = (nt < 2) ? mlo : mhi;
        u32 sh = (nt & 1) << 4;
        float e0 = exp2fast(s_[qb][nt][0]) * (float)((word >> (sh + 0)) & 1);
        float e1 = exp2fast(s_[qb][nt][1]) * (float)((word >> (sh + 1)) & 1);
        float e2 = exp2fast(s_[qb][nt][2]) * (float)((word >> (sh + 2)) & 1);
        float e3 = exp2fast(s_[qb][nt][3]) * (float)((word >> (sh + 3)) & 1);
        u32 pk0, pk1;
        asm("v_cvt_pk_bf16_f32 %0, %1, %2" : "=v"(pk0) : "v"(e0), "v"(e1));
        asm("v_cvt_pk_bf16_f32 %0, %1, %2" : "=v"(pk1) : "v"(e2), "v"(e3));
        uint2 pr; pr.x = pk0; pr.y = pk1;
        *(uint2*)((char*)Pw + (qb * 16 + r16) * 144 + nt * 32 + g * 8) = pr;
      }
    }
    asm volatile("" ::: "memory");               // same-wave LDS write -> read ordering

    // PV: o[qb][nt_d] += P @ V ; o4[qb] += P @ ones; each bv read feeds 2 MFMAs
    __builtin_amdgcn_s_setprio(1);
#pragma unroll
    for (int c = 0; c < 2; c++) {
      s16x8 pa0 = *(const s16x8*)((char*)Pw + r16 * 144 + c * 64 + g * 16);
      s16x8 pa1 = *(const s16x8*)((char*)Pw + (16 + r16) * 144 + c * 64 + g * 16);
#pragma unroll
      for (int nt = 0; nt < 4; nt++) {
        s16x8 bv = *(const s16x8*)((char*)&Vsh[cur][0][0] + (nt * 16 + r16) * 128 +
                                   (((c * 4 + g) ^ (r16 & 7)) << 4));
        o[0][nt] = MFMA(pa0, bv, o[0][nt]);
        o[1][nt] = MFMA(pa1, bv, o[1][nt]);
      }
      o4[0] = MFMA(pa0, vones, o4[0]);
      o4[1] = MFMA(pa1, vones, o4[1]);
    }
    __builtin_amdgcn_s_setprio(0);

    asm volatile("s_barrier" ::: "memory");      // all waves done reading buf(cur)
    u64 mnew0 = 0, mnew1 = 0;
    if (t + 2 < 32) {                            // stage tile t+2 into buf(cur)
      STAGE(cur, (t + 2) * 64);
      mnew0 = Mrow0[t + 2];
      mnew1 = Mrow1[t + 2];
    }
    mcur0 = mnext0; mcur1 = mnext1;
    mnext0 = mnew0; mnext1 = mnew1;
  }
#undef STAGE

  // o4[qb][ri] = rowsum for q = qb*16 + g*4 + ri -> direct normalization, then write
#pragma unroll
  for (int qb = 0; qb < 2; qb++) {
    float invq[4];
#pragma unroll
    for (int ri = 0; ri < 4; ri++) invq[ri] = 1.f / o4[qb][ri];
#pragma unroll
    for (int nt = 0; nt < 4; nt++) {
      int col = (h << 6) + nt * 16 + r16;
#pragma unroll
      for (int ri = 0; ri < 4; ri++) {
        int row = (b << 11) + q0 + qb * 16 + g * 4 + ri;
        ctx[((size_t)row << 10) + col] = f2bf(o[qb][nt][ri] * invq[ri]);
      }
    }
  }
}

// ---------- host ----------
extern "C" void kernel_launch(void* const* d_in, const int* in_sizes, int n_in,
                              void* d_out, int out_size, void* d_ws, size_t ws_size,
                              hipStream_t stream) {
  const float* query = (const float*)d_in[0];
  const float* key_  = (const float*)d_in[1];
  const float* value = (const float*)d_in[2];
  const int*   mask  = (const int*)d_in[3];
  const float* Wq = (const float*)d_in[4];
  const float* bq = (const float*)d_in[5];
  const float* Wk = (const float*)d_in[6];
  const float* bk = (const float*)d_in[7];
  const float* Wv = (const float*)d_in[8];
  const float* bv = (const float*)d_in[9];
  const float* Wo = (const float*)d_in[10];
  const float* bo = (const float*)d_in[11];

  const size_t MB = 1048576;
  char* ws = (char*)d_ws;
  u16* Xq  = (u16*)(ws + 0 * MB);
  u16* Xk  = (u16*)(ws + 8 * MB);
  u16* Xv  = (u16*)(ws + 16 * MB);
  u16* WqT = (u16*)(ws + 24 * MB);
  u16* WkT = (u16*)(ws + 26 * MB);
  u16* WvT = (u16*)(ws + 28 * MB);
  u16* WoT = (u16*)(ws + 30 * MB);
  u16* Qd  = (u16*)(ws + 32 * MB);
  u16* Kd  = (u16*)(ws + 40 * MB);
  u16* Vtd = (u16*)(ws + 48 * MB);
  u16* ctx = (u16*)(ws + 56 * MB);
  u64* Mb  = (u64*)(ws + 72 * MB);   // 1 MB bitmask

  cvt_bf16_3<<<dim3(2048, 3), 256, 0, stream>>>(query, key_, value, Xq, Xk, Xv);
  mask_bits<<<32768, 256, 0, stream>>>(mask, Mb);

  dim3 tb(32, 8);
  transpose_w4<<<dim3(32, 32, 4), tb, 0, stream>>>(Wq, Wk, Wv, Wo, WqT, WkT, WvT, WoT);

  proj_gemm<<<dim3(8, 32, 3), 256, 0, stream>>>(Xq, Xk, Xv, WqT, WkT, WvT, bq, bk, bv,
                                                Qd, Kd, Vtd);
  flash_attn<<<dim3(16, 16, 2), 256, 0, stream>>>(Qd, Kd, Vtd, Mb, ctx);
  out_gemm<<<dim3(8, 64), 256, 0, stream>>>(ctx, WoT, bo, (float*)d_out);
}

// Round 7
// 157.355 us; speedup vs baseline: 2.3354x; 1.0102x over previous
//
#include <hip/hip_runtime.h>

typedef __attribute__((ext_vector_type(8))) short s16x8;
typedef __attribute__((ext_vector_type(4))) float f32x4;
typedef __attribute__((ext_vector_type(16))) float f32x16;
typedef unsigned short u16;
typedef unsigned int u32;
typedef unsigned long long u64;

// ---------- helpers ----------
__device__ __forceinline__ u16 f2bf(float f) {            // RNE f32 -> bf16
  u32 u = __builtin_bit_cast(u32, f);
  u += 0x7fff + ((u >> 16) & 1);
  return (u16)(u >> 16);
}

__device__ __forceinline__ float exp2fast(float x) {
#if __has_builtin(__builtin_amdgcn_exp2f)
  return __builtin_amdgcn_exp2f(x);
#else
  return __expf(x * 0.6931471805599453f);
#endif
}

__device__ __forceinline__ void gload16(const void* g, void* l) {
  __builtin_amdgcn_global_load_lds((const __attribute__((address_space(1))) u32*)g,
                                   (__attribute__((address_space(3))) u32*)l, 16, 0, 0);
}

#define MFMA(a, b, c) __builtin_amdgcn_mfma_f32_16x16x32_bf16((a), (b), (c), 0, 0, 0)
#define MFMA32(a, b, c) __builtin_amdgcn_mfma_f32_32x32x16_bf16((a), (b), (c), 0, 0, 0)

// scale * log2(e), folded into Q at projection time
#define QSCALE 0.18033688011112042f

// ---------- fp32 -> bf16 convert, 3 tensors fused (8 elems/thread) ----------
__global__ __launch_bounds__(256) void cvt_bf16_3(const float* __restrict__ q,
                                                  const float* __restrict__ k,
                                                  const float* __restrict__ v,
                                                  u16* __restrict__ oq, u16* __restrict__ ok,
                                                  u16* __restrict__ ov) {
  int z = blockIdx.y;
  const float* src = (z == 0) ? q : (z == 1) ? k : v;
  u16* dst = (z == 0) ? oq : (z == 1) ? ok : ov;
  int i = blockIdx.x * 256 + threadIdx.x;
  const float4* s4 = (const float4*)src;
  float4 a = s4[2 * i], b = s4[2 * i + 1];
  uint4 o;
  o.x = (u32)f2bf(a.x) | ((u32)f2bf(a.y) << 16);
  o.y = (u32)f2bf(a.z) | ((u32)f2bf(a.w) << 16);
  o.z = (u32)f2bf(b.x) | ((u32)f2bf(b.y) << 16);
  o.w = (u32)f2bf(b.z) | ((u32)f2bf(b.w) << 16);
  ((uint4*)dst)[i] = o;
}

// ---------- mask int32 [B,S,S] -> bitmask u64 [B,S,S/64] ----------
__global__ __launch_bounds__(256) void mask_bits(const int* __restrict__ mask,
                                                 u64* __restrict__ mb) {
  int wi = (blockIdx.x * 256 + threadIdx.x) >> 6;   // u64 index, one wave each
  int lane = threadIdx.x & 63;
  u64 bits = __ballot(mask[((size_t)wi << 6) + lane] != 0);
  if (lane == 0) mb[wi] = bits;
}

// ---------- 4x W [1024][1024] f32 -> WT [1024][1024] bf16, fused ----------
__global__ __launch_bounds__(256) void transpose_w4(const float* __restrict__ W0,
                                                    const float* __restrict__ W1,
                                                    const float* __restrict__ W2,
                                                    const float* __restrict__ W3,
                                                    u16* __restrict__ T0, u16* __restrict__ T1,
                                                    u16* __restrict__ T2, u16* __restrict__ T3) {
  int z = blockIdx.z;
  const float* W = (z == 0) ? W0 : (z == 1) ? W1 : (z == 2) ? W2 : W3;
  u16* WT = (z == 0) ? T0 : (z == 1) ? T1 : (z == 2) ? T2 : T3;
  __shared__ float t[32][33];
  int tx = threadIdx.x, ty = threadIdx.y;
  int n = blockIdx.x * 32 + tx;
#pragma unroll
  for (int j = 0; j < 4; j++) {
    int k = blockIdx.y * 32 + ty + 8 * j;
    t[ty + 8 * j][tx] = W[(size_t)k * 1024 + n];
  }
  __syncthreads();
  int k = blockIdx.y * 32 + tx;
#pragma unroll
  for (int j = 0; j < 4; j++) {
    int n2 = blockIdx.x * 32 + ty + 8 * j;
    WT[(size_t)n2 * 1024 + k] = f2bf(t[tx][ty + 8 * j]);
  }
}

// ---------- pipelined GEMM core (dist-2 dbuf, counted vmcnt, chunk swizzle) ----------
template <int BM, int BN>
__device__ __forceinline__ void gemm_core(const u16* __restrict__ A, const u16* __restrict__ BT,
                                          int m0, int n0, u16* Ash, u16* Bsh,
                                          f32x4 (&acc)[BM / 32][BN / 32]) {
  constexpr int MF = BM / 32, NF = BN / 32;
  constexpr int BATCH = BM / 32 + BN / 32;   // gload16 per thread per K-tile
  const int tid = threadIdx.x;
  const int lane = tid & 63, wid = tid >> 6;
  const int r16 = lane & 15, g = lane >> 4;
  const int wm = wid >> 1, wn = wid & 1;
  const int swz = r16 & 7;
  const f32x4 vz = {0.f, 0.f, 0.f, 0.f};
#pragma unroll
  for (int mf = 0; mf < MF; mf++)
#pragma unroll
    for (int nf = 0; nf < NF; nf++) acc[mf][nf] = vz;

  auto stage = [&](int buf, int k0) {
#pragma unroll
    for (int i = 0; i < MF; i++) {
      int ch = i * 256 + tid;
      int row = ch >> 3, sc = (ch & 7) ^ (row & 7);
      gload16(A + (((size_t)(m0 + row)) << 10) + k0 + sc * 8,
              Ash + (size_t)buf * (BM * 64) + ch * 8);
    }
#pragma unroll
    for (int i = 0; i < NF; i++) {
      int ch = i * 256 + tid;
      int row = ch >> 3, sc = (ch & 7) ^ (row & 7);
      gload16(BT + (((size_t)(n0 + row)) << 10) + k0 + sc * 8,
              Bsh + (size_t)buf * (BN * 64) + ch * 8);
    }
  };

  asm volatile("" ::: "memory");
  stage(0, 0);
  asm volatile("" ::: "memory");
  stage(1, 64);
  asm volatile("" ::: "memory");

  for (int t = 0; t < 16; t++) {
    const int cur = t & 1;
    if (t == 15) {
      asm volatile("s_waitcnt vmcnt(0)" ::: "memory");
    } else if constexpr (BATCH == 8) {
      asm volatile("s_waitcnt vmcnt(8)" ::: "memory");
    } else {
      asm volatile("s_waitcnt vmcnt(6)" ::: "memory");
    }
    asm volatile("s_barrier" ::: "memory");      // buf(cur) ready

    const u16* Acur = Ash + (size_t)cur * (BM * 64);
    const u16* Bcur = Bsh + (size_t)cur * (BN * 64);
    __builtin_amdgcn_s_setprio(1);
#pragma unroll
    for (int kk = 0; kk < 2; kk++) {
      const int c = (kk * 4 + g);
      s16x8 af[MF], bfr[NF];
#pragma unroll
      for (int mf = 0; mf < MF; mf++)
        af[mf] = *(const s16x8*)(Acur + ((wm * (BM / 2) + mf * 16 + r16) << 6) +
                                 ((c ^ swz) << 3));
#pragma unroll
      for (int nf = 0; nf < NF; nf++)
        bfr[nf] = *(const s16x8*)(Bcur + ((wn * (BN / 2) + nf * 16 + r16) << 6) +
                                  ((c ^ swz) << 3));
#pragma unroll
      for (int mf = 0; mf < MF; mf++)
#pragma unroll
        for (int nf = 0; nf < NF; nf++) acc[mf][nf] = MFMA(af[mf], bfr[nf], acc[mf][nf]);
    }
    __builtin_amdgcn_s_setprio(0);

    asm volatile("s_barrier" ::: "memory");      // all waves done reading buf(cur)
    if (t + 2 < 16) stage(cur, (t + 2) * 64);    // refill freed buffer
  }
}

// ---------- fused QKV projection: z=0 Q (pre-scaled), z=1 K, z=2 V (transposed) ----------
__global__ __launch_bounds__(256, 2) void proj_gemm(
    const u16* __restrict__ Xq, const u16* __restrict__ Xk, const u16* __restrict__ Xv,
    const u16* __restrict__ WqT, const u16* __restrict__ WkT, const u16* __restrict__ WvT,
    const float* __restrict__ bq, const float* __restrict__ bk, const float* __restrict__ bv,
    u16* __restrict__ Qo, u16* __restrict__ Ko, u16* __restrict__ Vto) {
  __shared__ u16 Ash[2 * 128 * 64], Bsh[2 * 128 * 64];
  const int z = blockIdx.z;
  const u16* A = (z == 0) ? Xq : (z == 1) ? Xk : Xv;
  const u16* BT = (z == 0) ? WqT : (z == 1) ? WkT : WvT;
  const float* bias = (z == 0) ? bq : (z == 1) ? bk : bv;
  u16* O = (z == 0) ? Qo : (z == 1) ? Ko : Vto;
  const float sc = (z == 0) ? QSCALE : 1.0f;
  const int m0 = blockIdx.y * 128, n0 = blockIdx.x * 128;
  f32x4 acc[4][4];
  gemm_core<128, 128>(A, BT, m0, n0, Ash, Bsh, acc);
  const int tid = threadIdx.x, lane = tid & 63, wid = tid >> 6;
  const int r16 = lane & 15, g = lane >> 4, wm = wid >> 1, wn = wid & 1;
#pragma unroll
  for (int nf = 0; nf < 4; nf++) {
    int col = n0 + wn * 64 + nf * 16 + r16;
    float bb = bias[col];
    int h = col >> 6, d = col & 63;
#pragma unroll
    for (int mf = 0; mf < 4; mf++) {
#pragma unroll
      for (int ri = 0; ri < 4; ri++) {
        int row = m0 + wm * 64 + mf * 16 + g * 4 + ri;
        int b_ = row >> 11, s_ = row & 2047;
        u16 val = f2bf((acc[mf][nf][ri] + bb) * sc);
        if (z < 2)
          O[((((size_t)b_ * 16 + h) * 2048 + s_) << 6) + d] = val;     // [B,H,S,64]
        else
          O[((((size_t)b_ * 16 + h) * 64 + d) << 11) + s_] = val;     // [B,H,64,S]
      }
    }
  }
}

// ---------- output projection: out = ctx @ WoT^T + bo (fp32) ----------
__global__ __launch_bounds__(256, 2) void out_gemm(const u16* __restrict__ ctx,
                                                   const u16* __restrict__ WoT,
                                                   const float* __restrict__ bo,
                                                   float* __restrict__ out) {
  __shared__ u16 Ash[2 * 64 * 64], Bsh[2 * 128 * 64];
  const int m0 = blockIdx.y * 64, n0 = blockIdx.x * 128;
  f32x4 acc[2][4];
  gemm_core<64, 128>(ctx, WoT, m0, n0, Ash, Bsh, acc);
  const int tid = threadIdx.x, lane = tid & 63, wid = tid >> 6;
  const int r16 = lane & 15, g = lane >> 4, wm = wid >> 1, wn = wid & 1;
#pragma unroll
  for (int nf = 0; nf < 4; nf++) {
    int col = n0 + wn * 64 + nf * 16 + r16;
    float bb = bo[col];
#pragma unroll
    for (int mf = 0; mf < 2; mf++) {
#pragma unroll
      for (int ri = 0; ri < 4; ri++) {
        int row = m0 + wm * 32 + mf * 16 + g * 4 + ri;
        out[((size_t)row << 10) + col] = acc[mf][nf][ri] + bb;
      }
    }
  }
}

// ---------- softmax + in-register P->A-frag pack (32x32 C layout) ----------
__device__ __forceinline__ s16x8 pack4u(u32 a0, u32 a1, u32 b0, u32 b1) {
  union { u32 u[4]; s16x8 v; } p;
  p.u[0] = a0; p.u[1] = a1; p.u[2] = b0; p.u[3] = b1;
  return p.v;
}

__device__ __forceinline__ void softpack(const f32x16& sv, u32 wm, s16x8& pA, s16x8& pB) {
  float e[16];
#pragma unroll
  for (int qd = 0; qd < 4; qd++)
#pragma unroll
    for (int j = 0; j < 4; j++)
      e[qd * 4 + j] = exp2fast(sv[qd * 4 + j]) * (float)((wm >> (qd * 8 + j)) & 1);
#pragma unroll
  for (int n = 0; n < 2; n++) {
    u32 a0, a1, b0, b1;
    asm("v_cvt_pk_bf16_f32 %0, %1, %2" : "=v"(a0) : "v"(e[n * 8 + 0]), "v"(e[n * 8 + 1]));
    asm("v_cvt_pk_bf16_f32 %0, %1, %2" : "=v"(a1) : "v"(e[n * 8 + 2]), "v"(e[n * 8 + 3]));
    asm("v_cvt_pk_bf16_f32 %0, %1, %2" : "=v"(b0) : "v"(e[n * 8 + 4]), "v"(e[n * 8 + 5]));
    asm("v_cvt_pk_bf16_f32 %0, %1, %2" : "=v"(b1) : "v"(e[n * 8 + 6]), "v"(e[n * 8 + 7]));
    // exchange halves: after swap, a' holds w0 data for both halves, b' holds w2
    asm("v_permlane32_swap_b32 %0, %1" : "+v"(a0), "+v"(b0));
    asm("v_permlane32_swap_b32 %0, %1" : "+v"(a1), "+v"(b1));
    if (n == 0) pA = pack4u(a0, a1, b0, b1);
    else        pB = pack4u(a0, a1, b0, b1);
  }
}

// ---------- flash attention v6: 32x32 MFMA, in-register softmax, XCD swizzle ----------
// block = 4 waves x 32 q = 128 q; kv tiles of 64 staged in LDS (dist-2, vmcnt(5)).
// P never touches LDS: swapped QK^T (32x32) keeps kv split only across lane
// halves -> cvt_pk + v_permlane32_swap builds PV A-frags in registers.
__global__ __launch_bounds__(256, 2) void flash_attn(const u16* __restrict__ Q,
                                                     const u16* __restrict__ K,
                                                     const u16* __restrict__ Vt,
                                                     const u64* __restrict__ Mb64,
                                                     u16* __restrict__ ctx) {
  __shared__ __align__(16) u16 Ksh[2][64][64];  // [buf][kv][d]   chunk-swizzled
  __shared__ __align__(16) u16 Vsh[2][64][64];  // [buf][d][kv]   chunk-swizzled

  const int tid = threadIdx.x, w = tid >> 6, lane = tid & 63;
  const int l31 = lane & 31, h5 = lane >> 5, l7 = lane & 7;

  // XCD-chunked swizzle: all 16 q-tiles of one (b,h) land on one XCD's L2
  int work = ((int)blockIdx.x & 7) * 64 + ((int)blockIdx.x >> 3);
  const int qt = work & 15, bh = work >> 4;     // bh = b*16+h
  const int b = bh >> 4, h = bh & 15;
  const int q0 = qt * 128 + w * 32;             // wave's 32 q rows

  const u16* Qb = Q + ((size_t)bh << 17);
  const u16* Kb = K + ((size_t)bh << 17);
  const u16* Vb = Vt + ((size_t)bh << 17);
  const u64* Mrow = Mb64 + ((size_t)(b * 2048 + q0 + l31) << 5);  // 32 u64 per q-row

  const int srow = tid >> 3, sk16 = tid & 7;
#define STAGE(buf, kv0)                                                                   \
  {                                                                                       \
    _Pragma("unroll") for (int i = 0; i < 2; i++) {                                       \
      int row = i * 32 + srow;                                                            \
      int sc = sk16 ^ (row & 7);                                                          \
      gload16(Kb + (((size_t)((kv0) + row)) << 6) + sc * 8,                               \
              (char*)&Ksh[buf][0][0] + (i * 256 + tid) * 16);                             \
      gload16(Vb + (((size_t)row) << 11) + (kv0) + sc * 8,                                \
              (char*)&Vsh[buf][0][0] + (i * 256 + tid) * 16);                             \
    }                                                                                     \
  }

  // Q as B-fragment (pre-scaled): lane holds Q[q0+l31][dk*16 + h5*8 .. +7]
  s16x8 aq[4];
#pragma unroll
  for (int dk = 0; dk < 4; dk++)
    aq[dk] = *(const s16x8*)(Qb + ((q0 + l31) << 6) + dk * 16 + h5 * 8);
  asm volatile("" ::: "memory");   // pin: aq loads before batch0
  STAGE(0, 0);
  u64 mcur = Mrow[0];
  asm volatile("" ::: "memory");   // pin: batch0 before batch1
  STAGE(1, 64);
  u64 mnext = Mrow[1];
  asm volatile("" ::: "memory");

  s16x8 vones;
#pragma unroll
  for (int j = 0; j < 8; j++) vones[j] = (short)0x3F80;  // bf16 1.0

  f32x16 o0, o1, o4;
#pragma unroll
  for (int r = 0; r < 16; r++) { o0[r] = 0.f; o1[r] = 0.f; o4[r] = 0.f; }

  for (int t = 0; t < 32; t++) {
    const int cur = t & 1;
    if (t == 31) {
      asm volatile("s_waitcnt vmcnt(0)" ::: "memory");
    } else {
      asm volatile("s_waitcnt vmcnt(5)" ::: "memory");
    }
    asm volatile("s_barrier" ::: "memory");          // all waves: buf(cur) ready

    const u16* Kc = &Ksh[cur][0][0];
    const u16* Vc = &Vsh[cur][0][0];

    // S^T = K @ Q^T (32x32x16): s0 = kv 0..31, s1 = kv 32..63 of this tile
    f32x16 s0, s1;
#pragma unroll
    for (int r = 0; r < 16; r++) { s0[r] = 0.f; s1[r] = 0.f; }
    __builtin_amdgcn_s_setprio(1);
#pragma unroll
    for (int dk = 0; dk < 4; dk++) {
      int ch = (((dk << 1) + h5) ^ l7) << 3;
      s16x8 ak0 = *(const s16x8*)(Kc + (l31 << 6) + ch);
      s16x8 ak1 = *(const s16x8*)(Kc + ((32 + l31) << 6) + ch);
      s0 = MFMA32(ak0, aq[dk], s0);
      s1 = MFMA32(ak1, aq[dk], s1);
    }
    __builtin_amdgcn_s_setprio(0);

    // in-register softmax + pack: pa[km] = A-frag for kv 16-block km
    u64 msh = mcur >> (h5 << 2);
    s16x8 pa[4];
    softpack(s0, (u32)msh, pa[0], pa[1]);
    softpack(s1, (u32)(msh >> 32), pa[2], pa[3]);

    // PV: o[db] += P @ V ; o4 += P @ ones (row-sum, C-layout aligned)
    __builtin_amdgcn_s_setprio(1);
#pragma unroll
    for (int km = 0; km < 4; km++) {
      int ch = (((km << 1) + h5) ^ l7) << 3;
      s16x8 bv0 = *(const s16x8*)(Vc + (l31 << 6) + ch);
      s16x8 bv1 = *(const s16x8*)(Vc + ((32 + l31) << 6) + ch);
      o0 = MFMA32(pa[km], bv0, o0);
      o1 = MFMA32(pa[km], bv1, o1);
      o4 = MFMA32(pa[km], vones, o4);
    }
    __builtin_amdgcn_s_setprio(0);

    asm volatile("s_barrier" ::: "memory");      // all waves done reading buf(cur)
    u64 mnew = 0;
    if (t + 2 < 32) {                            // stage tile t+2 into buf(cur)
      STAGE(cur, (t + 2) * 64);
      mnew = Mrow[t + 2];
    }
    mcur = mnext;
    mnext = mnew;
  }
#undef STAGE

  // o4[r] = rowsum for q = q0 + (r&3)+8*(r>>2)+4*h5 -> normalize + write ctx bf16
#pragma unroll
  for (int r = 0; r < 16; r++) {
    int qr = (r & 3) + 8 * (r >> 2) + 4 * h5;
    size_t rowoff = ((size_t)((b << 11) + q0 + qr)) << 10;
    float iv = 1.f / o4[r];
    ctx[rowoff + (h << 6) + l31]      = f2bf(o0[r] * iv);
    ctx[rowoff + (h << 6) + 32 + l31] = f2bf(o1[r] * iv);
  }
}

// ---------- host ----------
extern "C" void kernel_launch(void* const* d_in, const int* in_sizes, int n_in,
                              void* d_out, int out_size, void* d_ws, size_t ws_size,
                              hipStream_t stream) {
  const float* query = (const float*)d_in[0];
  const float* key_  = (const float*)d_in[1];
  const float* value = (const float*)d_in[2];
  const int*   mask  = (const int*)d_in[3];
  const float* Wq = (const float*)d_in[4];
  const float* bq = (const float*)d_in[5];
  const float* Wk = (const float*)d_in[6];
  const float* bk = (const float*)d_in[7];
  const float* Wv = (const float*)d_in[8];
  const float* bv = (const float*)d_in[9];
  const float* Wo = (const float*)d_in[10];
  const float* bo = (const float*)d_in[11];

  const size_t MB = 1048576;
  char* ws = (char*)d_ws;
  u16* Xq  = (u16*)(ws + 0 * MB);
  u16* Xk  = (u16*)(ws + 8 * MB);
  u16* Xv  = (u16*)(ws + 16 * MB);
  u16* WqT = (u16*)(ws + 24 * MB);
  u16* WkT = (u16*)(ws + 26 * MB);
  u16* WvT = (u16*)(ws + 28 * MB);
  u16* WoT = (u16*)(ws + 30 * MB);
  u16* Qd  = (u16*)(ws + 32 * MB);
  u16* Kd  = (u16*)(ws + 40 * MB);
  u16* Vtd = (u16*)(ws + 48 * MB);
  u16* ctx = (u16*)(ws + 56 * MB);
  u64* Mb  = (u64*)(ws + 72 * MB);   // 1 MB bitmask

  cvt_bf16_3<<<dim3(2048, 3), 256, 0, stream>>>(query, key_, value, Xq, Xk, Xv);
  mask_bits<<<32768, 256, 0, stream>>>(mask, Mb);

  dim3 tb(32, 8);
  transpose_w4<<<dim3(32, 32, 4), tb, 0, stream>>>(Wq, Wk, Wv, Wo, WqT, WkT, WvT, WoT);

  proj_gemm<<<dim3(8, 32, 3), 256, 0, stream>>>(Xq, Xk, Xv, WqT, WkT, WvT, bq, bk, bv,
                                                Qd, Kd, Vtd);
  flash_attn<<<512, 256, 0, stream>>>(Qd, Kd, Vtd, Mb, ctx);
  out_gemm<<<dim3(8, 64), 256, 0, stream>>>(ctx, WoT, bo, (float*)d_out);
}

// Round 8
// 156.862 us; speedup vs baseline: 2.3428x; 1.0031x over previous
//
#include <hip/hip_runtime.h>

typedef __attribute__((ext_vector_type(8))) short s16x8;
typedef __attribute__((ext_vector_type(4))) float f32x4;
typedef __attribute__((ext_vector_type(16))) float f32x16;
typedef unsigned short u16;
typedef unsigned int u32;
typedef unsigned long long u64;

// ---------- helpers ----------
__device__ __forceinline__ u16 f2bf(float f) {            // RNE f32 -> bf16
  u32 u = __builtin_bit_cast(u32, f);
  u += 0x7fff + ((u >> 16) & 1);
  return (u16)(u >> 16);
}

__device__ __forceinline__ float exp2fast(float x) {
#if __has_builtin(__builtin_amdgcn_exp2f)
  return __builtin_amdgcn_exp2f(x);
#else
  return __expf(x * 0.6931471805599453f);
#endif
}

__device__ __forceinline__ void gload16(const void* g, void* l) {
  __builtin_amdgcn_global_load_lds((const __attribute__((address_space(1))) u32*)g,
                                   (__attribute__((address_space(3))) u32*)l, 16, 0, 0);
}

#define MFMA(a, b, c) __builtin_amdgcn_mfma_f32_16x16x32_bf16((a), (b), (c), 0, 0, 0)
#define MFMA32(a, b, c) __builtin_amdgcn_mfma_f32_32x32x16_bf16((a), (b), (c), 0, 0, 0)

// scale * log2(e), folded into Q at projection time
#define QSCALE 0.18033688011112042f

// ---------- fp32 -> bf16 convert, 3 tensors fused (8 elems/thread) ----------
__global__ __launch_bounds__(256) void cvt_bf16_3(const float* __restrict__ q,
                                                  const float* __restrict__ k,
                                                  const float* __restrict__ v,
                                                  u16* __restrict__ oq, u16* __restrict__ ok,
                                                  u16* __restrict__ ov) {
  int z = blockIdx.y;
  const float* src = (z == 0) ? q : (z == 1) ? k : v;
  u16* dst = (z == 0) ? oq : (z == 1) ? ok : ov;
  int i = blockIdx.x * 256 + threadIdx.x;
  const float4* s4 = (const float4*)src;
  float4 a = s4[2 * i], b = s4[2 * i + 1];
  uint4 o;
  o.x = (u32)f2bf(a.x) | ((u32)f2bf(a.y) << 16);
  o.y = (u32)f2bf(a.z) | ((u32)f2bf(a.w) << 16);
  o.z = (u32)f2bf(b.x) | ((u32)f2bf(b.y) << 16);
  o.w = (u32)f2bf(b.z) | ((u32)f2bf(b.w) << 16);
  ((uint4*)dst)[i] = o;
}

// ---------- mask int32 [B,S,S] -> bitmask u64 [B,S,S/64] ----------
__global__ __launch_bounds__(256) void mask_bits(const int* __restrict__ mask,
                                                 u64* __restrict__ mb) {
  int wi = (blockIdx.x * 256 + threadIdx.x) >> 6;   // u64 index, one wave each
  int lane = threadIdx.x & 63;
  u64 bits = __ballot(mask[((size_t)wi << 6) + lane] != 0);
  if (lane == 0) mb[wi] = bits;
}

// ---------- 4x W [1024][1024] f32 -> WT [1024][1024] bf16, fused ----------
__global__ __launch_bounds__(256) void transpose_w4(const float* __restrict__ W0,
                                                    const float* __restrict__ W1,
                                                    const float* __restrict__ W2,
                                                    const float* __restrict__ W3,
                                                    u16* __restrict__ T0, u16* __restrict__ T1,
                                                    u16* __restrict__ T2, u16* __restrict__ T3) {
  int z = blockIdx.z;
  const float* W = (z == 0) ? W0 : (z == 1) ? W1 : (z == 2) ? W2 : W3;
  u16* WT = (z == 0) ? T0 : (z == 1) ? T1 : (z == 2) ? T2 : T3;
  __shared__ float t[32][33];
  int tx = threadIdx.x, ty = threadIdx.y;
  int n = blockIdx.x * 32 + tx;
#pragma unroll
  for (int j = 0; j < 4; j++) {
    int k = blockIdx.y * 32 + ty + 8 * j;
    t[ty + 8 * j][tx] = W[(size_t)k * 1024 + n];
  }
  __syncthreads();
  int k = blockIdx.y * 32 + tx;
#pragma unroll
  for (int j = 0; j < 4; j++) {
    int n2 = blockIdx.x * 32 + ty + 8 * j;
    WT[(size_t)n2 * 1024 + k] = f2bf(t[tx][ty + 8 * j]);
  }
}

// ---------- pipelined GEMM core (dist-2 dbuf, counted vmcnt, chunk swizzle) ----------
template <int BM, int BN>
__device__ __forceinline__ void gemm_core(const u16* __restrict__ A, const u16* __restrict__ BT,
                                          int m0, int n0, u16* Ash, u16* Bsh,
                                          f32x4 (&acc)[BM / 32][BN / 32]) {
  constexpr int MF = BM / 32, NF = BN / 32;
  constexpr int BATCH = BM / 32 + BN / 32;   // gload16 per thread per K-tile
  const int tid = threadIdx.x;
  const int lane = tid & 63, wid = tid >> 6;
  const int r16 = lane & 15, g = lane >> 4;
  const int wm = wid >> 1, wn = wid & 1;
  const int swz = r16 & 7;
  const f32x4 vz = {0.f, 0.f, 0.f, 0.f};
#pragma unroll
  for (int mf = 0; mf < MF; mf++)
#pragma unroll
    for (int nf = 0; nf < NF; nf++) acc[mf][nf] = vz;

  auto stage = [&](int buf, int k0) {
#pragma unroll
    for (int i = 0; i < MF; i++) {
      int ch = i * 256 + tid;
      int row = ch >> 3, sc = (ch & 7) ^ (row & 7);
      gload16(A + (((size_t)(m0 + row)) << 10) + k0 + sc * 8,
              Ash + (size_t)buf * (BM * 64) + ch * 8);
    }
#pragma unroll
    for (int i = 0; i < NF; i++) {
      int ch = i * 256 + tid;
      int row = ch >> 3, sc = (ch & 7) ^ (row & 7);
      gload16(BT + (((size_t)(n0 + row)) << 10) + k0 + sc * 8,
              Bsh + (size_t)buf * (BN * 64) + ch * 8);
    }
  };

  asm volatile("" ::: "memory");
  stage(0, 0);
  asm volatile("" ::: "memory");
  stage(1, 64);
  asm volatile("" ::: "memory");

  for (int t = 0; t < 16; t++) {
    const int cur = t & 1;
    if (t == 15) {
      asm volatile("s_waitcnt vmcnt(0)" ::: "memory");
    } else if constexpr (BATCH == 8) {
      asm volatile("s_waitcnt vmcnt(8)" ::: "memory");
    } else {
      asm volatile("s_waitcnt vmcnt(6)" ::: "memory");
    }
    asm volatile("s_barrier" ::: "memory");      // buf(cur) ready

    const u16* Acur = Ash + (size_t)cur * (BM * 64);
    const u16* Bcur = Bsh + (size_t)cur * (BN * 64);
    __builtin_amdgcn_s_setprio(1);
#pragma unroll
    for (int kk = 0; kk < 2; kk++) {
      const int c = (kk * 4 + g);
      s16x8 af[MF], bfr[NF];
#pragma unroll
      for (int mf = 0; mf < MF; mf++)
        af[mf] = *(const s16x8*)(Acur + ((wm * (BM / 2) + mf * 16 + r16) << 6) +
                                 ((c ^ swz) << 3));
#pragma unroll
      for (int nf = 0; nf < NF; nf++)
        bfr[nf] = *(const s16x8*)(Bcur + ((wn * (BN / 2) + nf * 16 + r16) << 6) +
                                  ((c ^ swz) << 3));
#pragma unroll
      for (int mf = 0; mf < MF; mf++)
#pragma unroll
        for (int nf = 0; nf < NF; nf++) acc[mf][nf] = MFMA(af[mf], bfr[nf], acc[mf][nf]);
    }
    __builtin_amdgcn_s_setprio(0);

    asm volatile("s_barrier" ::: "memory");      // all waves done reading buf(cur)
    if (t + 2 < 16) stage(cur, (t + 2) * 64);    // refill freed buffer
  }
}

// ---------- fused QKV projection: z=0 Q (pre-scaled), z=1 K, z=2 V (transposed) ----------
__global__ __launch_bounds__(256, 2) void proj_gemm(
    const u16* __restrict__ Xq, const u16* __restrict__ Xk, const u16* __restrict__ Xv,
    const u16* __restrict__ WqT, const u16* __restrict__ WkT, const u16* __restrict__ WvT,
    const float* __restrict__ bq, const float* __restrict__ bk, const float* __restrict__ bv,
    u16* __restrict__ Qo, u16* __restrict__ Ko, u16* __restrict__ Vto) {
  __shared__ u16 Ash[2 * 128 * 64], Bsh[2 * 128 * 64];
  const int z = blockIdx.z;
  const u16* A = (z == 0) ? Xq : (z == 1) ? Xk : Xv;
  const u16* BT = (z == 0) ? WqT : (z == 1) ? WkT : WvT;
  const float* bias = (z == 0) ? bq : (z == 1) ? bk : bv;
  u16* O = (z == 0) ? Qo : (z == 1) ? Ko : Vto;
  const float sc = (z == 0) ? QSCALE : 1.0f;
  const int m0 = blockIdx.y * 128, n0 = blockIdx.x * 128;
  f32x4 acc[4][4];
  gemm_core<128, 128>(A, BT, m0, n0, Ash, Bsh, acc);
  const int tid = threadIdx.x, lane = tid & 63, wid = tid >> 6;
  const int r16 = lane & 15, g = lane >> 4, wm = wid >> 1, wn = wid & 1;
#pragma unroll
  for (int nf = 0; nf < 4; nf++) {
    int col = n0 + wn * 64 + nf * 16 + r16;
    float bb = bias[col];
    int h = col >> 6, d = col & 63;
#pragma unroll
    for (int mf = 0; mf < 4; mf++) {
#pragma unroll
      for (int ri = 0; ri < 4; ri++) {
        int row = m0 + wm * 64 + mf * 16 + g * 4 + ri;
        int b_ = row >> 11, s_ = row & 2047;
        u16 val = f2bf((acc[mf][nf][ri] + bb) * sc);
        if (z < 2)
          O[((((size_t)b_ * 16 + h) * 2048 + s_) << 6) + d] = val;     // [B,H,S,64]
        else
          O[((((size_t)b_ * 16 + h) * 64 + d) << 11) + s_] = val;     // [B,H,64,S]
      }
    }
  }
}

// ---------- output projection: out = ctx @ WoT^T + bo (fp32) ----------
__global__ __launch_bounds__(256, 2) void out_gemm(const u16* __restrict__ ctx,
                                                   const u16* __restrict__ WoT,
                                                   const float* __restrict__ bo,
                                                   float* __restrict__ out) {
  __shared__ u16 Ash[2 * 64 * 64], Bsh[2 * 128 * 64];
  const int m0 = blockIdx.y * 64, n0 = blockIdx.x * 128;
  f32x4 acc[2][4];
  gemm_core<64, 128>(ctx, WoT, m0, n0, Ash, Bsh, acc);
  const int tid = threadIdx.x, lane = tid & 63, wid = tid >> 6;
  const int r16 = lane & 15, g = lane >> 4, wm = wid >> 1, wn = wid & 1;
#pragma unroll
  for (int nf = 0; nf < 4; nf++) {
    int col = n0 + wn * 64 + nf * 16 + r16;
    float bb = bo[col];
#pragma unroll
    for (int mf = 0; mf < 2; mf++) {
#pragma unroll
      for (int ri = 0; ri < 4; ri++) {
        int row = m0 + wm * 32 + mf * 16 + g * 4 + ri;
        out[((size_t)row << 10) + col] = acc[mf][nf][ri] + bb;
      }
    }
  }
}

// ---------- softmax + in-register P->A-frag pack (32x32 C layout) ----------
__device__ __forceinline__ s16x8 pack4u(u32 a0, u32 a1, u32 b0, u32 b1) {
  union { u32 u[4]; s16x8 v; } p;
  p.u[0] = a0; p.u[1] = a1; p.u[2] = b0; p.u[3] = b1;
  return p.v;
}

__device__ __forceinline__ void softpack(const f32x16& sv, u32 wm, s16x8& pA, s16x8& pB) {
  float e[16];
#pragma unroll
  for (int qd = 0; qd < 4; qd++)
#pragma unroll
    for (int j = 0; j < 4; j++)
      e[qd * 4 + j] = exp2fast(sv[qd * 4 + j]) * (float)((wm >> (qd * 8 + j)) & 1);
#pragma unroll
  for (int n = 0; n < 2; n++) {
    u32 a0, a1, b0, b1;
    asm("v_cvt_pk_bf16_f32 %0, %1, %2" : "=v"(a0) : "v"(e[n * 8 + 0]), "v"(e[n * 8 + 1]));
    asm("v_cvt_pk_bf16_f32 %0, %1, %2" : "=v"(a1) : "v"(e[n * 8 + 2]), "v"(e[n * 8 + 3]));
    asm("v_cvt_pk_bf16_f32 %0, %1, %2" : "=v"(b0) : "v"(e[n * 8 + 4]), "v"(e[n * 8 + 5]));
    asm("v_cvt_pk_bf16_f32 %0, %1, %2" : "=v"(b1) : "v"(e[n * 8 + 6]), "v"(e[n * 8 + 7]));
    // exchange halves: after swap, a' holds w0 data for both halves, b' holds w2
    asm("v_permlane32_swap_b32 %0, %1" : "+v"(a0), "+v"(b0));
    asm("v_permlane32_swap_b32 %0, %1" : "+v"(a1), "+v"(b1));
    if (n == 0) pA = pack4u(a0, a1, b0, b1);
    else        pB = pack4u(a0, a1, b0, b1);
  }
}

// ---------- flash attention v7: cross-tile software pipeline ----------
// block = 4 waves x 32 q = 128 q; kv tiles of 64, 2-buffer 2-barrier staging.
// Pipeline: iteration t issues QK^T(t), then softpack(t-1) VALU runs under those
// MFMAs, then PV(t-1) from register-cached V fragments (read in iteration t-1).
// Iteration 0 runs a harmless zero pipeline (sp=0,mask=0 -> pa=0; V regs zeroed).
__global__ __launch_bounds__(256, 2) void flash_attn(const u16* __restrict__ Q,
                                                     const u16* __restrict__ K,
                                                     const u16* __restrict__ Vt,
                                                     const u64* __restrict__ Mb64,
                                                     u16* __restrict__ ctx) {
  __shared__ __align__(16) u16 Ksh[2][64][64];  // [buf][kv][d]   chunk-swizzled
  __shared__ __align__(16) u16 Vsh[2][64][64];  // [buf][d][kv]   chunk-swizzled

  const int tid = threadIdx.x, w = tid >> 6, lane = tid & 63;
  const int l31 = lane & 31, h5 = lane >> 5, l7 = lane & 7;

  // XCD-chunked swizzle: all 16 q-tiles of one (b,h) land on one XCD's L2
  int work = ((int)blockIdx.x & 7) * 64 + ((int)blockIdx.x >> 3);
  const int qt = work & 15, bh = work >> 4;     // bh = b*16+h
  const int b = bh >> 4, h = bh & 15;
  const int q0 = qt * 128 + w * 32;             // wave's 32 q rows

  const u16* Qb = Q + ((size_t)bh << 17);
  const u16* Kb = K + ((size_t)bh << 17);
  const u16* Vb = Vt + ((size_t)bh << 17);
  const u64* Mrow = Mb64 + ((size_t)(b * 2048 + q0 + l31) << 5);  // 32 u64 per q-row

  const int srow = tid >> 3, sk16 = tid & 7;
#define STAGE(buf, kv0)                                                                   \
  {                                                                                       \
    _Pragma("unroll") for (int i = 0; i < 2; i++) {                                       \
      int row = i * 32 + srow;                                                            \
      int sc = sk16 ^ (row & 7);                                                          \
      gload16(Kb + (((size_t)((kv0) + row)) << 6) + sc * 8,                               \
              (char*)&Ksh[buf][0][0] + (i * 256 + tid) * 16);                             \
      gload16(Vb + (((size_t)row) << 11) + (kv0) + sc * 8,                                \
              (char*)&Vsh[buf][0][0] + (i * 256 + tid) * 16);                             \
    }                                                                                     \
  }

  // Q as B-fragment (pre-scaled): lane holds Q[q0+l31][dk*16 + h5*8 .. +7]
  s16x8 aq[4];
#pragma unroll
  for (int dk = 0; dk < 4; dk++)
    aq[dk] = *(const s16x8*)(Qb + ((q0 + l31) << 6) + dk * 16 + h5 * 8);
  asm volatile("" ::: "memory");   // pin: aq loads before batch0
  STAGE(0, 0);
  u64 m_c = Mrow[0];               // mask(t)   for t=0
  asm volatile("" ::: "memory");   // pin: batch0 before batch1
  STAGE(1, 64);
  u64 m_n = Mrow[1];               // mask(t+1)
  asm volatile("" ::: "memory");
  u64 m_pp = 0;                    // mask(t-1): all-masked -> iteration-0 pipeline is a no-op

  s16x8 vones, z8;
#pragma unroll
  for (int j = 0; j < 8; j++) { vones[j] = (short)0x3F80; z8[j] = 0; }  // bf16 1.0 / 0

  f32x16 o0, o1, o4, sp0, sp1;
#pragma unroll
  for (int r = 0; r < 16; r++) { o0[r] = 0.f; o1[r] = 0.f; o4[r] = 0.f; sp0[r] = 0.f; sp1[r] = 0.f; }
  s16x8 vrA[4], vrB[4];            // register-cached V fragments of tile t-1 (zero: no NaN)
#pragma unroll
  for (int km = 0; km < 4; km++) { vrA[km] = z8; vrB[km] = z8; }

  for (int t = 0; t < 32; t++) {
    const int cur = t & 1;
    if (t == 31) {
      asm volatile("s_waitcnt vmcnt(0)" ::: "memory");
    } else {
      asm volatile("s_waitcnt vmcnt(5)" ::: "memory");
    }
    asm volatile("s_barrier" ::: "memory");          // all waves: buf(cur) ready

    const u16* Kc = &Ksh[cur][0][0];
    const u16* Vc = &Vsh[cur][0][0];

    // QK^T(t) (32x32x16): s0 = kv 0..31, s1 = kv 32..63 of tile t
    f32x16 s0, s1;
#pragma unroll
    for (int r = 0; r < 16; r++) { s0[r] = 0.f; s1[r] = 0.f; }
    __builtin_amdgcn_s_setprio(1);
#pragma unroll
    for (int dk = 0; dk < 4; dk++) {
      int ch = (((dk << 1) + h5) ^ l7) << 3;
      s16x8 ak0 = *(const s16x8*)(Kc + (l31 << 6) + ch);
      s16x8 ak1 = *(const s16x8*)(Kc + ((32 + l31) << 6) + ch);
      s0 = MFMA32(ak0, aq[dk], s0);
      s1 = MFMA32(ak1, aq[dk], s1);
    }
    __builtin_amdgcn_s_setprio(0);

    // softpack(t-1): VALU overlaps the QK^T(t) MFMAs above
    u64 msh = m_pp >> (h5 << 2);
    s16x8 pa[4];
    softpack(sp0, (u32)msh, pa[0], pa[1]);
    softpack(sp1, (u32)(msh >> 32), pa[2], pa[3]);

    // PV(t-1): uses register-cached V fragments, no LDS dependency
    __builtin_amdgcn_s_setprio(1);
#pragma unroll
    for (int km = 0; km < 4; km++) {
      o0 = MFMA32(pa[km], vrA[km], o0);
      o1 = MFMA32(pa[km], vrB[km], o1);
      o4 = MFMA32(pa[km], vones, o4);
    }
    __builtin_amdgcn_s_setprio(0);

    // V-fragment reads for tile t (consumed next iteration)
#pragma unroll
    for (int km = 0; km < 4; km++) {
      int ch = (((km << 1) + h5) ^ l7) << 3;
      vrA[km] = *(const s16x8*)(Vc + (l31 << 6) + ch);
      vrB[km] = *(const s16x8*)(Vc + ((32 + l31) << 6) + ch);
    }
    asm volatile("s_waitcnt lgkmcnt(0)" ::: "memory");  // V reads landed before restage
    asm volatile("s_barrier" ::: "memory");             // all waves done with buf(cur)
    u64 m_new = 0;
    if (t + 2 < 32) {                                   // stage tile t+2 into buf(cur)
      STAGE(cur, (t + 2) * 64);
      m_new = Mrow[t + 2];
    }
    m_pp = m_c; m_c = m_n; m_n = m_new;
    sp0 = s0; sp1 = s1;
  }
#undef STAGE

  // drain pipeline: softpack + PV for tile 31
  {
    u64 msh = m_pp >> (h5 << 2);
    s16x8 pa[4];
    softpack(sp0, (u32)msh, pa[0], pa[1]);
    softpack(sp1, (u32)(msh >> 32), pa[2], pa[3]);
#pragma unroll
    for (int km = 0; km < 4; km++) {
      o0 = MFMA32(pa[km], vrA[km], o0);
      o1 = MFMA32(pa[km], vrB[km], o1);
      o4 = MFMA32(pa[km], vones, o4);
    }
  }

  // o4[r] = rowsum for q = q0 + (r&3)+8*(r>>2)+4*h5 -> normalize + write ctx bf16
#pragma unroll
  for (int r = 0; r < 16; r++) {
    int qr = (r & 3) + 8 * (r >> 2) + 4 * h5;
    size_t rowoff = ((size_t)((b << 11) + q0 + qr)) << 10;
    float iv = 1.f / o4[r];
    ctx[rowoff + (h << 6) + l31]      = f2bf(o0[r] * iv);
    ctx[rowoff + (h << 6) + 32 + l31] = f2bf(o1[r] * iv);
  }
}

// ---------- host ----------
extern "C" void kernel_launch(void* const* d_in, const int* in_sizes, int n_in,
                              void* d_out, int out_size, void* d_ws, size_t ws_size,
                              hipStream_t stream) {
  const float* query = (const float*)d_in[0];
  const float* key_  = (const float*)d_in[1];
  const float* value = (const float*)d_in[2];
  const int*   mask  = (const int*)d_in[3];
  const float* Wq = (const float*)d_in[4];
  const float* bq = (const float*)d_in[5];
  const float* Wk = (const float*)d_in[6];
  const float* bk = (const float*)d_in[7];
  const float* Wv = (const float*)d_in[8];
  const float* bv = (const float*)d_in[9];
  const float* Wo = (const float*)d_in[10];
  const float* bo = (const float*)d_in[11];

  const size_t MB = 1048576;
  char* ws = (char*)d_ws;
  u16* Xq  = (u16*)(ws + 0 * MB);
  u16* Xk  = (u16*)(ws + 8 * MB);
  u16* Xv  = (u16*)(ws + 16 * MB);
  u16* WqT = (u16*)(ws + 24 * MB);
  u16* WkT = (u16*)(ws + 26 * MB);
  u16* WvT = (u16*)(ws + 28 * MB);
  u16* WoT = (u16*)(ws + 30 * MB);
  u16* Qd  = (u16*)(ws + 32 * MB);
  u16* Kd  = (u16*)(ws + 40 * MB);
  u16* Vtd = (u16*)(ws + 48 * MB);
  u16* ctx = (u16*)(ws + 56 * MB);
  u64* Mb  = (u64*)(ws + 72 * MB);   // 1 MB bitmask

  cvt_bf16_3<<<dim3(2048, 3), 256, 0, stream>>>(query, key_, value, Xq, Xk, Xv);
  mask_bits<<<32768, 256, 0, stream>>>(mask, Mb);

  dim3 tb(32, 8);
  transpose_w4<<<dim3(32, 32, 4), tb, 0, stream>>>(Wq, Wk, Wv, Wo, WqT, WkT, WvT, WoT);

  proj_gemm<<<dim3(8, 32, 3), 256, 0, stream>>>(Xq, Xk, Xv, WqT, WkT, WvT, bq, bk, bv,
                                                Qd, Kd, Vtd);
  flash_attn<<<512, 256, 0, stream>>>(Qd, Kd, Vtd, Mb, ctx);
  out_gemm<<<dim3(8, 64), 256, 0, stream>>>(ctx, WoT, bo, (float*)d_out);
}